// Round 13
// baseline (125.947 us; speedup 1.0000x reference)
//
#include <hip/hip_runtime.h>
#include <math.h>

#define N_NODES 50000
#define N_EDGES 800000
#define IN_DIM 256
#define HID 64
#define BKT 256
#define NBKT ((N_NODES + BKT - 1) / BKT)          // 196
#define CAP 8192                                  // ebuf slots per bucket (max real ~4400)
#define CHUNK 4096
#define NCH ((N_EDGES + CHUNK - 1) / CHUNK)       // 196
#define NGB ((N_NODES + 63) / 64)                 // 782

typedef short short8v __attribute__((ext_vector_type(8)));
typedef float f32x4 __attribute__((ext_vector_type(4)));
typedef unsigned uint4v __attribute__((ext_vector_type(4)));

__device__ __forceinline__ unsigned short f2bf(float f) {
  unsigned u = __builtin_bit_cast(unsigned, f);
  u += 0x7FFFu + ((u >> 16) & 1u);  // RNE
  return (unsigned short)(u >> 16);
}
__device__ __forceinline__ unsigned pack2(float a, float b) {
  return (unsigned)f2bf(a) | ((unsigned)f2bf(b) << 16);
}
__device__ __forceinline__ float bfu_lo(unsigned u) {
  return __builtin_bit_cast(float, u << 16);
}
__device__ __forceinline__ float bfu_hi(unsigned u) {
  return __builtin_bit_cast(float, u & 0xFFFF0000u);
}

// ---------------- prep: zero bcur + convert/transpose weights ----------------
__global__ void k_prep(int* __restrict__ bcur, const float* __restrict__ W1,
                       const float* __restrict__ W2, unsigned short* __restrict__ Wt1,
                       unsigned short* __restrict__ Wt2) {
  const int t = threadIdx.x;
  if (blockIdx.x == 0) {
    bcur[t] = 0;
  } else if (blockIdx.x == 1) {
    for (int j = 0; j < 64; ++j) {
      int lin = j * 256 + t;
      int k = lin >> 6, c = lin & 63;
      Wt1[c * 256 + k] = f2bf(W1[lin]);
    }
  } else {
    for (int j = 0; j < 16; ++j) {
      int lin = j * 256 + t;
      int k = lin >> 6, c = lin & 63;
      Wt2[c * 64 + k] = f2bf(W2[lin]);
    }
  }
}

// ---------------- fused: GEMM1 (blocks 0..NGB) || split (blocks NGB..) ----------------
// GEMM1: outA[r][c] = bf16( sum_k X[r][k]*W1[k][c] )  -- UNSCALED (bucket scales in place)
__global__ __launch_bounds__(256) void k_g1split(
    const float* __restrict__ X, const unsigned short* __restrict__ Wt1g,
    unsigned short* __restrict__ outA, const int* __restrict__ src,
    const int* __restrict__ dst, int* __restrict__ bcur, unsigned* __restrict__ ebuf) {
  __shared__ unsigned short Wl[64][IN_DIM + 8];  // gemm1 branch (33.8KB)
  __shared__ int cnt[NBKT];                      // split branch
  __shared__ int cur[NBKT];
  const int t = threadIdx.x;
  if (blockIdx.x < NGB) {
    const int lane = t & 63, wv = t >> 6;
#pragma unroll
    for (int j = 0; j < 8; ++j) {
      int grp = j * 256 + t;
      int r = grp >> 5, c = (grp & 31) * 8;
      *reinterpret_cast<short8v*>(&Wl[r][c]) =
          *reinterpret_cast<const short8v*>(&Wt1g[r * IN_DIM + c]);
    }
    const int row0 = blockIdx.x * 64;
    int r = row0 + wv * 16 + (lane & 15);
    if (r > N_NODES - 1) r = N_NODES - 1;  // clamp (stores guarded)
    const int kh = (lane >> 4) * 8;

    uint4v ap[8];
#pragma unroll
    for (int k0 = 0; k0 < 8; ++k0) {
      const float* Xp = X + (size_t)r * IN_DIM + k0 * 32 + kh;
      const float4 x0 = *reinterpret_cast<const float4*>(Xp);
      const float4 x1 = *reinterpret_cast<const float4*>(Xp + 4);
      uint4v p;
      p.x = pack2(x0.x, x0.y); p.y = pack2(x0.z, x0.w);
      p.z = pack2(x1.x, x1.y); p.w = pack2(x1.z, x1.w);
      ap[k0] = p;
    }
    __syncthreads();

    f32x4 acc[4] = {};
#pragma unroll
    for (int k0 = 0; k0 < 8; ++k0) {
      short8v a = __builtin_bit_cast(short8v, ap[k0]);
#pragma unroll
      for (int n = 0; n < 4; ++n) {
        short8v b = *reinterpret_cast<const short8v*>(&Wl[n * 16 + (lane & 15)][k0 * 32 + kh]);
        acc[n] = __builtin_amdgcn_mfma_f32_16x16x32_bf16(a, b, acc[n], 0, 0, 0);
      }
    }

    const int r0 = row0 + wv * 16;
#pragma unroll
    for (int j = 0; j < 4; ++j) {
      int rr = r0 + (lane >> 4) * 4 + j;
      if (rr < N_NODES) {
#pragma unroll
        for (int n = 0; n < 4; ++n)
          outA[(size_t)rr * 64 + n * 16 + (lane & 15)] = f2bf(acc[n][j]);
      }
    }
  } else {
    // ---- split: edges -> padded bucket regions (packed u32: src<<8 | dstLocal) ----
    for (int i = t; i < NBKT; i += 256) cnt[i] = 0;
    __syncthreads();
    const int base = (blockIdx.x - NGB) * CHUNK;
#pragma unroll
    for (int i = 0; i < CHUNK / 256; ++i) {
      int e = base + i * 256 + t;
      if (e < N_EDGES) atomicAdd(&cnt[dst[e] >> 8], 1);
    }
    __syncthreads();
    for (int i = t; i < NBKT; i += 256) {
      int c = cnt[i];
      cur[i] = c ? (i * CAP + atomicAdd(&bcur[i], c)) : 0;
    }
    __syncthreads();
#pragma unroll
    for (int i = 0; i < CHUNK / 256; ++i) {
      int e = base + i * 256 + t;
      if (e < N_EDGES) {
        int d = dst[e];
        int p = atomicAdd(&cur[d >> 8], 1);
        ebuf[p] = ((unsigned)src[e] << 8) | (unsigned)(d & 255);
      }
    }
  }
}

// ---------------- bucket: fine CSR + dinv + in-place h'-scaling ----------------
__global__ void k_bucket(const unsigned* __restrict__ ebuf, const int* __restrict__ bcur,
                         int* __restrict__ rowptr, int* __restrict__ colidx,
                         float* __restrict__ dinv, unsigned short* __restrict__ hbuf) {
  __shared__ int sA[256];
  __shared__ int sB[256];
  __shared__ float sD[256];
  const int b = blockIdx.x, t = threadIdx.x;

  sA[t] = (t < NBKT) ? bcur[t] : 0;
  __syncthreads();
  for (int d = 1; d < 256; d <<= 1) {
    int v = sA[t];
    int a = (t >= d) ? sA[t - d] : 0;
    __syncthreads();
    sA[t] = v + a;
    __syncthreads();
  }
  const int prefix = (b == 0) ? 0 : sA[b - 1];
  const int cntb = bcur[b];
  const int sbeg = b * CAP, send = sbeg + cntb;
  __syncthreads();

  sA[t] = 0;
  __syncthreads();
  for (int i = sbeg + t; i < send; i += 256) atomicAdd(&sA[ebuf[i] & 255], 1);
  __syncthreads();
  const int myc = sA[t];
  sB[t] = myc;
  __syncthreads();
  for (int d = 1; d < 256; d <<= 1) {
    int v = sB[t];
    int a = (t >= d) ? sB[t - d] : 0;
    __syncthreads();
    sB[t] = v + a;
    __syncthreads();
  }
  const int node = b * BKT + t;
  const bool valid = node < N_NODES;
  const int ex = prefix + sB[t] - myc;
  const float dv = rsqrtf((float)(myc + 1));
  sD[t] = dv;
  if (valid) {
    rowptr[node] = ex;
    dinv[node] = dv;
    if (node == N_NODES - 1) rowptr[N_NODES] = N_EDGES;
  }
  __syncthreads();
  sB[t] = ex;
  __syncthreads();
  for (int i = sbeg + t; i < send; i += 256) {
    unsigned p = ebuf[i];
    int pos = atomicAdd(&sB[p & 255], 1);
    colidx[pos] = (int)(p >> 8);
  }

  // in-place scale of this bucket's h rows: h'[v] = dinv[v]*h[v]
  const int rsub = t >> 3, f8 = (t & 7) * 8;
#pragma unroll
  for (int g = 0; g < 8; ++g) {
    int lr = g * 32 + rsub;
    int nd = b * BKT + lr;
    if (nd < N_NODES) {
      float s = sD[lr];
      unsigned short* hp = &hbuf[(size_t)nd * 64 + f8];
      uint4 hv = *reinterpret_cast<const uint4*>(hp);
      uint4 o;
      o.x = pack2(s * bfu_lo(hv.x), s * bfu_hi(hv.x));
      o.y = pack2(s * bfu_lo(hv.y), s * bfu_hi(hv.y));
      o.z = pack2(s * bfu_lo(hv.z), s * bfu_hi(hv.z));
      o.w = pack2(s * bfu_lo(hv.w), s * bfu_hi(hv.w));
      *reinterpret_cast<uint4*>(hp) = o;
    }
  }
}

// ---------------- half-row gather body (4 lanes/node, 16 nodes/wave) ----------------
#define EHALF(hbuf, cc)                                                          \
  {                                                                              \
    uint4 w = *reinterpret_cast<const uint4*>(&hbuf[(size_t)(cc) * 64 + foff]);  \
    a0 += bfu_lo(w.x); a1 += bfu_hi(w.x);                                        \
    a2 += bfu_lo(w.y); a3 += bfu_hi(w.y);                                        \
    a4 += bfu_lo(w.z); a5 += bfu_hi(w.z);                                        \
    a6 += bfu_lo(w.w); a7 += bfu_hi(w.w);                                        \
  }

#define GATHER_HALF(hbuf)                                                          \
  int e = rowptr[v];                                                               \
  const int end = rowptr[v + 1];                                                   \
  uint4 sw = *reinterpret_cast<const uint4*>(&hbuf[(size_t)v * 64 + foff]);        \
  float a0 = bfu_lo(sw.x), a1 = bfu_hi(sw.x);                                      \
  float a2 = bfu_lo(sw.y), a3 = bfu_hi(sw.y);                                      \
  float a4 = bfu_lo(sw.z), a5 = bfu_hi(sw.z);                                      \
  float a6 = bfu_lo(sw.w), a7 = bfu_hi(sw.w);                                      \
  while (e < end && (e & 3)) { EHALF(hbuf, col[e]); ++e; }                         \
  for (; e + 8 <= end; e += 8) {                                                   \
    int4 ca = *reinterpret_cast<const int4*>(&col[e]);                             \
    int4 cb = *reinterpret_cast<const int4*>(&col[e + 4]);                         \
    EHALF(hbuf, ca.x); EHALF(hbuf, ca.y); EHALF(hbuf, ca.z); EHALF(hbuf, ca.w);    \
    EHALF(hbuf, cb.x); EHALF(hbuf, cb.y); EHALF(hbuf, cb.z); EHALF(hbuf, cb.w);    \
  }                                                                                \
  for (; e + 4 <= end; e += 4) {                                                   \
    int4 cc = *reinterpret_cast<const int4*>(&col[e]);                             \
    EHALF(hbuf, cc.x); EHALF(hbuf, cc.y); EHALF(hbuf, cc.z); EHALF(hbuf, cc.w);    \
  }                                                                                \
  for (; e < end; ++e) { EHALF(hbuf, col[e]); }

// ---------------- agg1 half-pass: h1[v][HALF*32..+32) = relu(sv*acc + b1) ----------------
template <int HALF>
__global__ __launch_bounds__(256) void k_agg1h(
    const unsigned short* __restrict__ h, const int* __restrict__ rowptr,
    const int* __restrict__ col, const float* __restrict__ dinv,
    const float* __restrict__ bias, unsigned short* __restrict__ h1) {
  const int t = threadIdx.x, lane = t & 63;
  const int grp = lane >> 2, foff = HALF * 32 + (lane & 3) * 8;
  const int v = blockIdx.x * 64 + (t >> 6) * 16 + grp;
  if (v >= N_NODES) return;

  GATHER_HALF(h)

  const float sv = dinv[v];
  const float4 ba = *reinterpret_cast<const float4*>(&bias[foff]);
  const float4 bb = *reinterpret_cast<const float4*>(&bias[foff + 4]);
  float v0 = fmaxf(fmaf(sv, a0, ba.x), 0.0f);
  float v1 = fmaxf(fmaf(sv, a1, ba.y), 0.0f);
  float v2 = fmaxf(fmaf(sv, a2, ba.z), 0.0f);
  float v3 = fmaxf(fmaf(sv, a3, ba.w), 0.0f);
  float v4 = fmaxf(fmaf(sv, a4, bb.x), 0.0f);
  float v5 = fmaxf(fmaf(sv, a5, bb.y), 0.0f);
  float v6 = fmaxf(fmaf(sv, a6, bb.z), 0.0f);
  float v7 = fmaxf(fmaf(sv, a7, bb.w), 0.0f);

  uint4 o;
  o.x = pack2(v0, v1); o.y = pack2(v2, v3);
  o.z = pack2(v4, v5); o.w = pack2(v6, v7);
  *reinterpret_cast<uint4*>(&h1[(size_t)v * 64 + foff]) = o;
}

// ---------------- GEMM2: h2'[r][c] = bf16( dinv[r] * sum_k h1[r][k]*W2[k][c] ) ----------------
__global__ __launch_bounds__(256) void k_gemm2(const unsigned short* __restrict__ h1,
                                               const unsigned short* __restrict__ Wt2g,
                                               const float* __restrict__ dinv,
                                               unsigned short* __restrict__ out) {
  const int t = threadIdx.x, lane = t & 63, wv = t >> 6;
  const int row0 = blockIdx.x * 64;
  int r = row0 + wv * 16 + (lane & 15);
  if (r > N_NODES - 1) r = N_NODES - 1;
  const int kh = (lane >> 4) * 8;

  f32x4 acc[4] = {};
#pragma unroll
  for (int k0 = 0; k0 < 64; k0 += 32) {
    short8v a = *reinterpret_cast<const short8v*>(&h1[(size_t)r * 64 + k0 + kh]);
#pragma unroll
    for (int n = 0; n < 4; ++n) {
      short8v b = *reinterpret_cast<const short8v*>(
          Wt2g + (size_t)(n * 16 + (lane & 15)) * 64 + k0 + kh);
      acc[n] = __builtin_amdgcn_mfma_f32_16x16x32_bf16(a, b, acc[n], 0, 0, 0);
    }
  }

  const int r0 = row0 + wv * 16;
#pragma unroll
  for (int j = 0; j < 4; ++j) {
    int rr = r0 + (lane >> 4) * 4 + j;
    if (rr < N_NODES) {
      float s = dinv[rr];
#pragma unroll
      for (int n = 0; n < 4; ++n)
        out[(size_t)rr * 64 + n * 16 + (lane & 15)] = f2bf(acc[n][j] * s);
    }
  }
}

// ---------------- agg2 half-pass + classifier partial dot ----------------
template <int HALF>
__global__ __launch_bounds__(256) void k_agg2(
    const unsigned short* __restrict__ h, const int* __restrict__ rowptr,
    const int* __restrict__ col, const float* __restrict__ dinv,
    const float* __restrict__ bias, const float* __restrict__ Wc,
    const float* __restrict__ bc, float* __restrict__ pacc,
    float* __restrict__ out) {
  const int t = threadIdx.x, lane = t & 63;
  const int grp = lane >> 2, foff = HALF * 32 + (lane & 3) * 8;
  const int v = blockIdx.x * 64 + (t >> 6) * 16 + grp;
  if (v >= N_NODES) return;

  GATHER_HALF(h)

  const float sv = dinv[v];
  const float4 ba = *reinterpret_cast<const float4*>(&bias[foff]);
  const float4 bb = *reinterpret_cast<const float4*>(&bias[foff + 4]);
  const float4 wa = *reinterpret_cast<const float4*>(&Wc[foff]);
  const float4 wb = *reinterpret_cast<const float4*>(&Wc[foff + 4]);
  float p = fmaxf(fmaf(sv, a0, ba.x), 0.0f) * wa.x +
            fmaxf(fmaf(sv, a1, ba.y), 0.0f) * wa.y +
            fmaxf(fmaf(sv, a2, ba.z), 0.0f) * wa.z +
            fmaxf(fmaf(sv, a3, ba.w), 0.0f) * wa.w +
            fmaxf(fmaf(sv, a4, bb.x), 0.0f) * wb.x +
            fmaxf(fmaf(sv, a5, bb.y), 0.0f) * wb.y +
            fmaxf(fmaf(sv, a6, bb.z), 0.0f) * wb.z +
            fmaxf(fmaf(sv, a7, bb.w), 0.0f) * wb.w;
  p += __shfl_xor(p, 1);
  p += __shfl_xor(p, 2);
  if ((lane & 3) == 0) {
    if (HALF == 0) {
      pacc[v] = p;
    } else {
      out[v] = 1.0f / (1.0f + expf(-(p + pacc[v] + bc[0])));
    }
  }
}

extern "C" void kernel_launch(void* const* d_in, const int* in_sizes, int n_in,
                              void* d_out, int out_size, void* d_ws, size_t ws_size,
                              hipStream_t stream) {
  const float* x  = (const float*)d_in[0];
  const int*   ei = (const int*)d_in[1];
  const float* W1 = (const float*)d_in[2];
  const float* b1 = (const float*)d_in[3];
  const float* W2 = (const float*)d_in[4];
  const float* b2 = (const float*)d_in[5];
  const float* Wc = (const float*)d_in[6];
  const float* bc = (const float*)d_in[7];
  float* out = (float*)d_out;

  const int* src = ei;
  const int* dst = ei + N_EDGES;

  // workspace layout (u32 units)
  unsigned* w = (unsigned*)d_ws;
  int*   bcur   = (int*)(w + 0);            // 256
  int*   rowptr = (int*)(w + 256);          // 50432 (needs 50001)
  int*   colidx = (int*)(w + 50688);        // 800000
  unsigned* ebuf = w + 850688;              // 196*8192 = 1605632
  float* dinv   = (float*)(w + 2456320);    // 50176
  float* pacc   = (float*)(w + 2506496);    // 50176
  unsigned short* Wt1g = (unsigned short*)(w + 2556672);  // 16384 ush
  unsigned short* Wt2g = (unsigned short*)(w + 2564864);  // 4096 ush
  unsigned short* A_bf = (unsigned short*)(w + 2566912);  // 3.2M ush
  unsigned short* B_bf = (unsigned short*)(w + 4166912);  // 3.2M ush

  k_prep<<<3, 256, 0, stream>>>(bcur, W1, W2, Wt1g, Wt2g);
  // GEMM1 (unscaled) runs concurrently with edge split in one dispatch
  k_g1split<<<NGB + NCH, 256, 0, stream>>>(x, Wt1g, A_bf, src, dst, bcur, ebuf);
  // CSR build + dinv + in-place scaling of h' rows (A_bf)
  k_bucket<<<NBKT, 256, 0, stream>>>(ebuf, bcur, rowptr, colidx, dinv, A_bf);

  const int NHB = (N_NODES + 63) / 64;  // 782 (64 nodes/block in half-passes)
  // layer 1 aggregate: two L2-resident half passes -> h1 (B_bf)
  k_agg1h<0><<<NHB, 256, 0, stream>>>(A_bf, rowptr, colidx, dinv, b1, B_bf);
  k_agg1h<1><<<NHB, 256, 0, stream>>>(A_bf, rowptr, colidx, dinv, b1, B_bf);
  // layer 2 GEMM: h1 -> h2' (A_bf, dinv-scaled)
  k_gemm2<<<NHB, 256, 0, stream>>>(B_bf, Wt2g, dinv, A_bf);
  // layer 2 aggregate + classifier: two half passes
  k_agg2<0><<<NHB, 256, 0, stream>>>(A_bf, rowptr, colidx, dinv, b2, Wc, bc, pacc, out);
  k_agg2<1><<<NHB, 256, 0, stream>>>(A_bf, rowptr, colidx, dinv, b2, Wc, bc, pacc, out);
}

// Round 14
// 97.890 us; speedup vs baseline: 1.2866x; 1.2866x over previous
//
#include <hip/hip_runtime.h>
#include <math.h>

#define N_NODES 50000
#define N_EDGES 800000
#define IN_DIM 256
#define HID 64
#define BKT 256
#define NBKT ((N_NODES + BKT - 1) / BKT)          // 196
#define CAP 8192                                  // ebuf slots per bucket (max real ~4400)
#define SEGC 5120                                 // LDS-cached entries per bucket (max real ~4340)
#define CHUNK 4096
#define NCH ((N_EDGES + CHUNK - 1) / CHUNK)       // 196
#define NGB ((N_NODES + 63) / 64)                 // 782

typedef short short8v __attribute__((ext_vector_type(8)));
typedef float f32x4 __attribute__((ext_vector_type(4)));
typedef unsigned uint4v __attribute__((ext_vector_type(4)));

__device__ __forceinline__ unsigned short f2bf(float f) {
  unsigned u = __builtin_bit_cast(unsigned, f);
  u += 0x7FFFu + ((u >> 16) & 1u);  // RNE
  return (unsigned short)(u >> 16);
}
__device__ __forceinline__ unsigned pack2(float a, float b) {
  return (unsigned)f2bf(a) | ((unsigned)f2bf(b) << 16);
}
__device__ __forceinline__ float bfu_lo(unsigned u) {
  return __builtin_bit_cast(float, u << 16);
}
__device__ __forceinline__ float bfu_hi(unsigned u) {
  return __builtin_bit_cast(float, u & 0xFFFF0000u);
}

// ---------------- prep: zero bcur + convert/transpose weights ----------------
__global__ void k_prep(int* __restrict__ bcur, const float* __restrict__ W1,
                       const float* __restrict__ W2, unsigned short* __restrict__ Wt1,
                       unsigned short* __restrict__ Wt2) {
  const int t = threadIdx.x;
  if (blockIdx.x == 0) {
    bcur[t] = 0;
  } else if (blockIdx.x == 1) {
    for (int j = 0; j < 64; ++j) {
      int lin = j * 256 + t;
      int k = lin >> 6, c = lin & 63;
      Wt1[c * 256 + k] = f2bf(W1[lin]);
    }
  } else {
    for (int j = 0; j < 16; ++j) {
      int lin = j * 256 + t;
      int k = lin >> 6, c = lin & 63;
      Wt2[c * 64 + k] = f2bf(W2[lin]);
    }
  }
}

// ---------------- fused: GEMM1 (blocks 0..NGB) || split (blocks NGB..) ----------------
// GEMM1: outA[r][c] = bf16( sum_k X[r][k]*W1[k][c] )  -- UNSCALED (bucket scales in place)
__global__ __launch_bounds__(256) void k_g1split(
    const float* __restrict__ X, const unsigned short* __restrict__ Wt1g,
    unsigned short* __restrict__ outA, const int* __restrict__ src,
    const int* __restrict__ dst, int* __restrict__ bcur, unsigned* __restrict__ ebuf) {
  __shared__ unsigned short Wl[64][IN_DIM + 8];  // gemm1 branch (33.8KB)
  __shared__ int cnt[NBKT];                      // split branch
  __shared__ int cur[NBKT];
  const int t = threadIdx.x;
  if (blockIdx.x < NGB) {
    const int lane = t & 63, wv = t >> 6;
#pragma unroll
    for (int j = 0; j < 8; ++j) {
      int grp = j * 256 + t;
      int r = grp >> 5, c = (grp & 31) * 8;
      *reinterpret_cast<short8v*>(&Wl[r][c]) =
          *reinterpret_cast<const short8v*>(&Wt1g[r * IN_DIM + c]);
    }
    const int row0 = blockIdx.x * 64;
    int r = row0 + wv * 16 + (lane & 15);
    if (r > N_NODES - 1) r = N_NODES - 1;  // clamp (stores guarded)
    const int kh = (lane >> 4) * 8;

    uint4v ap[8];
#pragma unroll
    for (int k0 = 0; k0 < 8; ++k0) {
      const float* Xp = X + (size_t)r * IN_DIM + k0 * 32 + kh;
      const float4 x0 = *reinterpret_cast<const float4*>(Xp);
      const float4 x1 = *reinterpret_cast<const float4*>(Xp + 4);
      uint4v p;
      p.x = pack2(x0.x, x0.y); p.y = pack2(x0.z, x0.w);
      p.z = pack2(x1.x, x1.y); p.w = pack2(x1.z, x1.w);
      ap[k0] = p;
    }
    __syncthreads();

    f32x4 acc[4] = {};
#pragma unroll
    for (int k0 = 0; k0 < 8; ++k0) {
      short8v a = __builtin_bit_cast(short8v, ap[k0]);
#pragma unroll
      for (int n = 0; n < 4; ++n) {
        short8v b = *reinterpret_cast<const short8v*>(&Wl[n * 16 + (lane & 15)][k0 * 32 + kh]);
        acc[n] = __builtin_amdgcn_mfma_f32_16x16x32_bf16(a, b, acc[n], 0, 0, 0);
      }
    }

    const int r0 = row0 + wv * 16;
#pragma unroll
    for (int j = 0; j < 4; ++j) {
      int rr = r0 + (lane >> 4) * 4 + j;
      if (rr < N_NODES) {
#pragma unroll
        for (int n = 0; n < 4; ++n)
          outA[(size_t)rr * 64 + n * 16 + (lane & 15)] = f2bf(acc[n][j]);
      }
    }
  } else {
    // ---- split: edges -> padded bucket regions (packed u32: src<<8 | dstLocal) ----
    for (int i = t; i < NBKT; i += 256) cnt[i] = 0;
    __syncthreads();
    const int base = (blockIdx.x - NGB) * CHUNK;
#pragma unroll
    for (int i = 0; i < CHUNK / 256; ++i) {
      int e = base + i * 256 + t;
      if (e < N_EDGES) atomicAdd(&cnt[dst[e] >> 8], 1);
    }
    __syncthreads();
    for (int i = t; i < NBKT; i += 256) {
      int c = cnt[i];
      cur[i] = c ? (i * CAP + atomicAdd(&bcur[i], c)) : 0;
    }
    __syncthreads();
#pragma unroll
    for (int i = 0; i < CHUNK / 256; ++i) {
      int e = base + i * 256 + t;
      if (e < N_EDGES) {
        int d = dst[e];
        int p = atomicAdd(&cur[d >> 8], 1);
        ebuf[p] = ((unsigned)src[e] << 8) | (unsigned)(d & 255);
      }
    }
  }
}

// ---------------- bucket: fine CSR + dinv + in-place h'-scaling ----------------
// ebuf segment cached in LDS once; hist + fill read LDS (overflow falls back to global).
__global__ void k_bucket(const unsigned* __restrict__ ebuf, const int* __restrict__ bcur,
                         int* __restrict__ rowptr, int* __restrict__ colidx,
                         float* __restrict__ dinv, unsigned short* __restrict__ hbuf) {
  __shared__ int sA[256];
  __shared__ int sB[256];
  __shared__ float sD[256];
  __shared__ unsigned seg[SEGC];  // 20KB
  const int b = blockIdx.x, t = threadIdx.x;

  const int cntb = bcur[b];
  const int sbeg = b * CAP;
  const int cached = cntb < SEGC ? cntb : SEGC;

  // issue LDS cache fill first; latency hides under the prefix scan below
  for (int i = t; i < cached; i += 256) seg[i] = ebuf[sbeg + i];

  // global colidx base via redundant scan of bucket counts
  sA[t] = (t < NBKT) ? bcur[t] : 0;
  __syncthreads();
  for (int d = 1; d < 256; d <<= 1) {
    int v = sA[t];
    int a = (t >= d) ? sA[t - d] : 0;
    __syncthreads();
    sA[t] = v + a;
    __syncthreads();
  }
  const int prefix = (b == 0) ? 0 : sA[b - 1];
  __syncthreads();

  // per-node degree within bucket (from LDS segment)
  sA[t] = 0;
  __syncthreads();
  for (int i = t; i < cached; i += 256) atomicAdd(&sA[seg[i] & 255], 1);
  for (int i = SEGC + t; i < cntb; i += 256) atomicAdd(&sA[ebuf[sbeg + i] & 255], 1);
  __syncthreads();
  const int myc = sA[t];
  sB[t] = myc;
  __syncthreads();
  for (int d = 1; d < 256; d <<= 1) {
    int v = sB[t];
    int a = (t >= d) ? sB[t - d] : 0;
    __syncthreads();
    sB[t] = v + a;
    __syncthreads();
  }
  const int node = b * BKT + t;
  const bool valid = node < N_NODES;
  const int ex = prefix + sB[t] - myc;
  const float dv = rsqrtf((float)(myc + 1));
  sD[t] = dv;
  if (valid) {
    rowptr[node] = ex;
    dinv[node] = dv;
    if (node == N_NODES - 1) rowptr[N_NODES] = N_EDGES;
  }
  __syncthreads();
  sB[t] = ex;  // per-node cursor
  __syncthreads();
  for (int i = t; i < cached; i += 256) {
    unsigned p = seg[i];
    int pos = atomicAdd(&sB[p & 255], 1);
    colidx[pos] = (int)(p >> 8);
  }
  for (int i = SEGC + t; i < cntb; i += 256) {
    unsigned p = ebuf[sbeg + i];
    int pos = atomicAdd(&sB[p & 255], 1);
    colidx[pos] = (int)(p >> 8);
  }

  // in-place scale of this bucket's h rows: h'[v] = dinv[v]*h[v]
  const int rsub = t >> 3, f8 = (t & 7) * 8;
#pragma unroll
  for (int g = 0; g < 8; ++g) {
    int lr = g * 32 + rsub;
    int nd = b * BKT + lr;
    if (nd < N_NODES) {
      float s = sD[lr];
      unsigned short* hp = &hbuf[(size_t)nd * 64 + f8];
      uint4 hv = *reinterpret_cast<const uint4*>(hp);
      uint4 o;
      o.x = pack2(s * bfu_lo(hv.x), s * bfu_hi(hv.x));
      o.y = pack2(s * bfu_lo(hv.y), s * bfu_hi(hv.y));
      o.z = pack2(s * bfu_lo(hv.z), s * bfu_hi(hv.z));
      o.w = pack2(s * bfu_lo(hv.w), s * bfu_hi(hv.w));
      *reinterpret_cast<uint4*>(hp) = o;
    }
  }
}

// ---------------- shared gather body: plain adds over pre-scaled h ----------------
#define EDGEP(hbuf, cc)                                                       \
  {                                                                           \
    uint4 w = *reinterpret_cast<const uint4*>(&hbuf[(size_t)(cc) * 64 + f0]); \
    acc0 += bfu_lo(w.x); acc1 += bfu_hi(w.x);                                 \
    acc2 += bfu_lo(w.y); acc3 += bfu_hi(w.y);                                 \
    acc4 += bfu_lo(w.z); acc5 += bfu_hi(w.z);                                 \
    acc6 += bfu_lo(w.w); acc7 += bfu_hi(w.w);                                 \
  }

#define GATHER_PLAIN(hbuf, EV, ENDV)                                               \
  uint4 sw = *reinterpret_cast<const uint4*>(&hbuf[(size_t)v * 64 + f0]);          \
  float acc0 = bfu_lo(sw.x), acc1 = bfu_hi(sw.x);                                  \
  float acc2 = bfu_lo(sw.y), acc3 = bfu_hi(sw.y);                                  \
  float acc4 = bfu_lo(sw.z), acc5 = bfu_hi(sw.z);                                  \
  float acc6 = bfu_lo(sw.w), acc7 = bfu_hi(sw.w);                                  \
  int e = EV;                                                                      \
  const int end = ENDV;                                                            \
  while (e < end && (e & 3)) { EDGEP(hbuf, col[e]); ++e; }                         \
  for (; e + 8 <= end; e += 8) {                                                   \
    int4 ca = *reinterpret_cast<const int4*>(&col[e]);                             \
    int4 cb = *reinterpret_cast<const int4*>(&col[e + 4]);                         \
    EDGEP(hbuf, ca.x); EDGEP(hbuf, ca.y); EDGEP(hbuf, ca.z); EDGEP(hbuf, ca.w);    \
    EDGEP(hbuf, cb.x); EDGEP(hbuf, cb.y); EDGEP(hbuf, cb.z); EDGEP(hbuf, cb.w);    \
  }                                                                                \
  for (; e + 4 <= end; e += 4) {                                                   \
    int4 cc = *reinterpret_cast<const int4*>(&col[e]);                             \
    EDGEP(hbuf, cc.x); EDGEP(hbuf, cc.y); EDGEP(hbuf, cc.z); EDGEP(hbuf, cc.w);    \
  }                                                                                \
  for (; e < end; ++e) { EDGEP(hbuf, col[e]); }

// ---------------- agg1 (plain adds) + bias/relu + GEMM2 fused ----------------
__global__ __launch_bounds__(256) void k_agg_gemm(
    const unsigned short* __restrict__ h, const int* __restrict__ rowptr,
    const int* __restrict__ col, const float* __restrict__ dinv,
    const float* __restrict__ bias, const unsigned short* __restrict__ Wt2g,
    unsigned short* __restrict__ out) {
  const int t = threadIdx.x, lane = t & 63, wv = t >> 6;
  const int g = lane >> 3, f0 = (lane & 7) * 8;
  const int vbase = blockIdx.x * 32;
  const int v = vbase + wv * 8 + g;
  const int lrow = wv * 8 + g;

  __shared__ unsigned short h1s[32][72];  // pad: 144B stride

  if (v < N_NODES) {
    const float sv = dinv[v];
    GATHER_PLAIN(h, rowptr[v], rowptr[v + 1])

    const float4 ba = *reinterpret_cast<const float4*>(&bias[f0]);
    const float4 bb = *reinterpret_cast<const float4*>(&bias[f0 + 4]);
    float v0 = fmaxf(fmaf(sv, acc0, ba.x), 0.0f);
    float v1 = fmaxf(fmaf(sv, acc1, ba.y), 0.0f);
    float v2 = fmaxf(fmaf(sv, acc2, ba.z), 0.0f);
    float v3 = fmaxf(fmaf(sv, acc3, ba.w), 0.0f);
    float v4 = fmaxf(fmaf(sv, acc4, bb.x), 0.0f);
    float v5 = fmaxf(fmaf(sv, acc5, bb.y), 0.0f);
    float v6 = fmaxf(fmaf(sv, acc6, bb.z), 0.0f);
    float v7 = fmaxf(fmaf(sv, acc7, bb.w), 0.0f);

    uint4 o;
    o.x = pack2(v0, v1); o.y = pack2(v2, v3);
    o.z = pack2(v4, v5); o.w = pack2(v6, v7);
    *reinterpret_cast<uint4*>(&h1s[lrow][f0]) = o;
  } else {
    uint4 z = {0, 0, 0, 0};
    *reinterpret_cast<uint4*>(&h1s[lrow][f0]) = z;
  }
  __syncthreads();

  // GEMM2: 32 nodes x 64 cols; wave wv owns cols [wv*16, wv*16+16); K=64.
  const int kh = (lane >> 4) * 8;
  f32x4 acc2r[2] = {};
#pragma unroll
  for (int rt = 0; rt < 2; ++rt) {
#pragma unroll
    for (int k0 = 0; k0 < 64; k0 += 32) {
      short8v a = *reinterpret_cast<const short8v*>(&h1s[rt * 16 + (lane & 15)][k0 + kh]);
      short8v b = *reinterpret_cast<const short8v*>(
          Wt2g + (size_t)(wv * 16 + (lane & 15)) * 64 + k0 + kh);
      acc2r[rt] = __builtin_amdgcn_mfma_f32_16x16x32_bf16(a, b, acc2r[rt], 0, 0, 0);
    }
  }
#pragma unroll
  for (int rt = 0; rt < 2; ++rt) {
#pragma unroll
    for (int j = 0; j < 4; ++j) {
      int vg = vbase + rt * 16 + (lane >> 4) * 4 + j;
      if (vg < N_NODES)
        out[(size_t)vg * 64 + wv * 16 + (lane & 15)] = f2bf(acc2r[rt][j] * dinv[vg]);
    }
  }
}

// ---------------- agg2 (plain adds) + classifier fused ----------------
__global__ __launch_bounds__(256) void k_agg_fin(
    const unsigned short* __restrict__ h, const int* __restrict__ rowptr,
    const int* __restrict__ col, const float* __restrict__ dinv,
    const float* __restrict__ bias, const float* __restrict__ Wc,
    const float* __restrict__ bc, float* __restrict__ out) {
  const int t = threadIdx.x, lane = t & 63;
  const int g = lane >> 3, f0 = (lane & 7) * 8;
  const int v = blockIdx.x * 32 + (t >> 6) * 8 + g;
  if (v >= N_NODES) return;

  GATHER_PLAIN(h, rowptr[v], rowptr[v + 1])

  const float sv = dinv[v];
  const float4 ba = *reinterpret_cast<const float4*>(&bias[f0]);
  const float4 bb = *reinterpret_cast<const float4*>(&bias[f0 + 4]);
  const float4 wa = *reinterpret_cast<const float4*>(&Wc[f0]);
  const float4 wb = *reinterpret_cast<const float4*>(&Wc[f0 + 4]);
  float p = fmaxf(fmaf(sv, acc0, ba.x), 0.0f) * wa.x +
            fmaxf(fmaf(sv, acc1, ba.y), 0.0f) * wa.y +
            fmaxf(fmaf(sv, acc2, ba.z), 0.0f) * wa.z +
            fmaxf(fmaf(sv, acc3, ba.w), 0.0f) * wa.w +
            fmaxf(fmaf(sv, acc4, bb.x), 0.0f) * wb.x +
            fmaxf(fmaf(sv, acc5, bb.y), 0.0f) * wb.y +
            fmaxf(fmaf(sv, acc6, bb.z), 0.0f) * wb.z +
            fmaxf(fmaf(sv, acc7, bb.w), 0.0f) * wb.w;
  p += __shfl_xor(p, 1);
  p += __shfl_xor(p, 2);
  p += __shfl_xor(p, 4);
  if ((lane & 7) == 0) out[v] = 1.0f / (1.0f + expf(-(p + bc[0])));
}

extern "C" void kernel_launch(void* const* d_in, const int* in_sizes, int n_in,
                              void* d_out, int out_size, void* d_ws, size_t ws_size,
                              hipStream_t stream) {
  const float* x  = (const float*)d_in[0];
  const int*   ei = (const int*)d_in[1];
  const float* W1 = (const float*)d_in[2];
  const float* b1 = (const float*)d_in[3];
  const float* W2 = (const float*)d_in[4];
  const float* b2 = (const float*)d_in[5];
  const float* Wc = (const float*)d_in[6];
  const float* bc = (const float*)d_in[7];
  float* out = (float*)d_out;

  const int* src = ei;
  const int* dst = ei + N_EDGES;

  // workspace layout (u32 units)
  unsigned* w = (unsigned*)d_ws;
  int*   bcur   = (int*)(w + 0);            // 256
  int*   rowptr = (int*)(w + 256);          // 50432 (needs 50001)
  int*   colidx = (int*)(w + 50688);        // 800000
  unsigned* ebuf = w + 850688;              // 196*8192 = 1605632
  float* dinv   = (float*)(w + 2456320);    // 50176
  unsigned short* Wt1g = (unsigned short*)(w + 2506496);  // 16384 ush
  unsigned short* Wt2g = (unsigned short*)(w + 2514688);  // 4096 ush
  unsigned short* A_bf = (unsigned short*)(w + 2516736);  // 3.2M ush
  unsigned short* B_bf = (unsigned short*)(w + 4116736);  // 3.2M ush

  k_prep<<<3, 256, 0, stream>>>(bcur, W1, W2, Wt1g, Wt2g);
  // GEMM1 (unscaled) runs concurrently with edge split in one dispatch
  k_g1split<<<NGB + NCH, 256, 0, stream>>>(x, Wt1g, A_bf, src, dst, bcur, ebuf);
  // CSR build + dinv + in-place scaling of h' rows (A_bf)
  k_bucket<<<NBKT, 256, 0, stream>>>(ebuf, bcur, rowptr, colidx, dinv, A_bf);

  const int NAB = (N_NODES + 31) / 32;  // 1563
  k_agg_gemm<<<NAB, 256, 0, stream>>>(A_bf, rowptr, colidx, dinv, b1, Wt2g, B_bf);
  k_agg_fin<<<NAB, 256, 0, stream>>>(B_bf, rowptr, colidx, dinv, b2, Wc, bc, out);
}

// Round 15
// 89.811 us; speedup vs baseline: 1.4024x; 1.0900x over previous
//
#include <hip/hip_runtime.h>
#include <math.h>

#define N_NODES 50000
#define N_EDGES 800000
#define IN_DIM 256
#define HID 64
#define BKT 256
#define NBKT ((N_NODES + BKT - 1) / BKT)          // 196
#define CAP 8192                                  // ebuf slots per bucket (max real ~4400)
#define SEGC 5120                                 // LDS-cached entries per bucket
#define CHUNK 4096
#define NCH ((N_EDGES + CHUNK - 1) / CHUNK)       // 196
#define NGB ((N_NODES + 63) / 64)                 // 782

typedef short short8v __attribute__((ext_vector_type(8)));
typedef float f32x4 __attribute__((ext_vector_type(4)));
typedef float f32x2 __attribute__((ext_vector_type(2)));
typedef unsigned uint4v __attribute__((ext_vector_type(4)));

__device__ __forceinline__ unsigned short f2bf(float f) {
  unsigned u = __builtin_bit_cast(unsigned, f);
  u += 0x7FFFu + ((u >> 16) & 1u);  // RNE
  return (unsigned short)(u >> 16);
}
__device__ __forceinline__ unsigned pack2(float a, float b) {
  return (unsigned)f2bf(a) | ((unsigned)f2bf(b) << 16);
}
__device__ __forceinline__ float bfu_lo(unsigned u) {
  return __builtin_bit_cast(float, u << 16);
}
__device__ __forceinline__ float bfu_hi(unsigned u) {
  return __builtin_bit_cast(float, u & 0xFFFF0000u);
}

// ---------------- prep: zero bcur + convert/transpose weights ----------------
__global__ void k_prep(int* __restrict__ bcur, const float* __restrict__ W1,
                       const float* __restrict__ W2, unsigned short* __restrict__ Wt1,
                       unsigned short* __restrict__ Wt2) {
  const int t = threadIdx.x;
  if (blockIdx.x == 0) {
    bcur[t] = 0;
  } else if (blockIdx.x == 1) {
    for (int j = 0; j < 64; ++j) {
      int lin = j * 256 + t;
      int k = lin >> 6, c = lin & 63;
      Wt1[c * 256 + k] = f2bf(W1[lin]);
    }
  } else {
    for (int j = 0; j < 16; ++j) {
      int lin = j * 256 + t;
      int k = lin >> 6, c = lin & 63;
      Wt2[c * 64 + k] = f2bf(W2[lin]);
    }
  }
}

// ---------------- fused: GEMM1 (blocks 0..NGB) || split (blocks NGB..) ----------------
// GEMM1: outA[r][c] = bf16( sum_k X[r][k]*W1[k][c] )  -- UNSCALED
__global__ __launch_bounds__(256) void k_g1split(
    const float* __restrict__ X, const unsigned short* __restrict__ Wt1g,
    unsigned short* __restrict__ outA, const int* __restrict__ src,
    const int* __restrict__ dst, int* __restrict__ bcur, unsigned* __restrict__ ebuf) {
  __shared__ unsigned short Wl[64][IN_DIM + 8];  // gemm1 branch (33.8KB)
  __shared__ int cnt[NBKT];                      // split branch
  __shared__ int cur[NBKT];
  const int t = threadIdx.x;
  if (blockIdx.x < NGB) {
    const int lane = t & 63, wv = t >> 6;
#pragma unroll
    for (int j = 0; j < 8; ++j) {
      int grp = j * 256 + t;
      int r = grp >> 5, c = (grp & 31) * 8;
      *reinterpret_cast<short8v*>(&Wl[r][c]) =
          *reinterpret_cast<const short8v*>(&Wt1g[r * IN_DIM + c]);
    }
    const int row0 = blockIdx.x * 64;
    int r = row0 + wv * 16 + (lane & 15);
    if (r > N_NODES - 1) r = N_NODES - 1;  // clamp (stores guarded)
    const int kh = (lane >> 4) * 8;

    uint4v ap[8];
#pragma unroll
    for (int k0 = 0; k0 < 8; ++k0) {
      const float* Xp = X + (size_t)r * IN_DIM + k0 * 32 + kh;
      const float4 x0 = *reinterpret_cast<const float4*>(Xp);
      const float4 x1 = *reinterpret_cast<const float4*>(Xp + 4);
      uint4v p;
      p.x = pack2(x0.x, x0.y); p.y = pack2(x0.z, x0.w);
      p.z = pack2(x1.x, x1.y); p.w = pack2(x1.z, x1.w);
      ap[k0] = p;
    }
    __syncthreads();

    f32x4 acc[4] = {};
#pragma unroll
    for (int k0 = 0; k0 < 8; ++k0) {
      short8v a = __builtin_bit_cast(short8v, ap[k0]);
#pragma unroll
      for (int n = 0; n < 4; ++n) {
        short8v b = *reinterpret_cast<const short8v*>(&Wl[n * 16 + (lane & 15)][k0 * 32 + kh]);
        acc[n] = __builtin_amdgcn_mfma_f32_16x16x32_bf16(a, b, acc[n], 0, 0, 0);
      }
    }

    const int r0 = row0 + wv * 16;
#pragma unroll
    for (int j = 0; j < 4; ++j) {
      int rr = r0 + (lane >> 4) * 4 + j;
      if (rr < N_NODES) {
#pragma unroll
        for (int n = 0; n < 4; ++n)
          outA[(size_t)rr * 64 + n * 16 + (lane & 15)] = f2bf(acc[n][j]);
      }
    }
  } else {
    // ---- split: edges -> padded bucket regions (packed u32: src<<8 | dstLocal) ----
    for (int i = t; i < NBKT; i += 256) cnt[i] = 0;
    __syncthreads();
    const int base = (blockIdx.x - NGB) * CHUNK;
#pragma unroll
    for (int i = 0; i < CHUNK / 256; ++i) {
      int e = base + i * 256 + t;
      if (e < N_EDGES) atomicAdd(&cnt[dst[e] >> 8], 1);
    }
    __syncthreads();
    for (int i = t; i < NBKT; i += 256) {
      int c = cnt[i];
      cur[i] = c ? (i * CAP + atomicAdd(&bcur[i], c)) : 0;
    }
    __syncthreads();
#pragma unroll
    for (int i = 0; i < CHUNK / 256; ++i) {
      int e = base + i * 256 + t;
      if (e < N_EDGES) {
        int d = dst[e];
        int p = atomicAdd(&cur[d >> 8], 1);
        ebuf[p] = ((unsigned)src[e] << 8) | (unsigned)(d & 255);
      }
    }
  }
}

// ---------------- bucket: fine CSR + dinv + scaled fp8 h1' emission ----------------
__global__ void k_bucket(const unsigned* __restrict__ ebuf, const int* __restrict__ bcur,
                         int* __restrict__ rowptr, int* __restrict__ colidx,
                         float* __restrict__ dinv, const unsigned short* __restrict__ hbf,
                         unsigned char* __restrict__ h8) {
  __shared__ int sA[256];
  __shared__ int sB[256];
  __shared__ float sD[256];
  __shared__ unsigned seg[SEGC];  // 20KB
  const int b = blockIdx.x, t = threadIdx.x;

  const int cntb = bcur[b];
  const int sbeg = b * CAP;
  const int cached = cntb < SEGC ? cntb : SEGC;

  // issue LDS cache fill first; latency hides under the prefix scan below
  for (int i = t; i < cached; i += 256) seg[i] = ebuf[sbeg + i];

  // global colidx base via redundant scan of bucket counts
  sA[t] = (t < NBKT) ? bcur[t] : 0;
  __syncthreads();
  for (int d = 1; d < 256; d <<= 1) {
    int v = sA[t];
    int a = (t >= d) ? sA[t - d] : 0;
    __syncthreads();
    sA[t] = v + a;
    __syncthreads();
  }
  const int prefix = (b == 0) ? 0 : sA[b - 1];
  __syncthreads();

  // per-node degree within bucket (from LDS segment)
  sA[t] = 0;
  __syncthreads();
  for (int i = t; i < cached; i += 256) atomicAdd(&sA[seg[i] & 255], 1);
  for (int i = SEGC + t; i < cntb; i += 256) atomicAdd(&sA[ebuf[sbeg + i] & 255], 1);
  __syncthreads();
  const int myc = sA[t];
  sB[t] = myc;
  __syncthreads();
  for (int d = 1; d < 256; d <<= 1) {
    int v = sB[t];
    int a = (t >= d) ? sB[t - d] : 0;
    __syncthreads();
    sB[t] = v + a;
    __syncthreads();
  }
  const int node = b * BKT + t;
  const bool valid = node < N_NODES;
  const int ex = prefix + sB[t] - myc;
  const float dv = rsqrtf((float)(myc + 1));
  sD[t] = dv;
  if (valid) {
    rowptr[node] = ex;
    dinv[node] = dv;
    if (node == N_NODES - 1) rowptr[N_NODES] = N_EDGES;
  }
  __syncthreads();
  sB[t] = ex;  // per-node cursor
  __syncthreads();
  for (int i = t; i < cached; i += 256) {
    unsigned p = seg[i];
    int pos = atomicAdd(&sB[p & 255], 1);
    colidx[pos] = (int)(p >> 8);
  }
  for (int i = SEGC + t; i < cntb; i += 256) {
    unsigned p = ebuf[sbeg + i];
    int pos = atomicAdd(&sB[p & 255], 1);
    colidx[pos] = (int)(p >> 8);
  }

  // emit h1'[v] = fp8_e4m3( dinv[v] * h[v] ) -- 64B rows, L2-resident for agg1
  const int rsub = t >> 3, f8 = (t & 7) * 8;
#pragma unroll
  for (int g = 0; g < 8; ++g) {
    int lr = g * 32 + rsub;
    int nd = b * BKT + lr;
    if (nd < N_NODES) {
      float s = sD[lr];
      const unsigned short* hp = &hbf[(size_t)nd * 64 + f8];
      uint4 hv = *reinterpret_cast<const uint4*>(hp);
      float v0 = s * bfu_lo(hv.x), v1 = s * bfu_hi(hv.x);
      float v2 = s * bfu_lo(hv.y), v3 = s * bfu_hi(hv.y);
      float v4 = s * bfu_lo(hv.z), v5 = s * bfu_hi(hv.z);
      float v6 = s * bfu_lo(hv.w), v7 = s * bfu_hi(hv.w);
      int lo = 0, hi = 0;
      lo = __builtin_amdgcn_cvt_pk_fp8_f32(v0, v1, lo, false);
      lo = __builtin_amdgcn_cvt_pk_fp8_f32(v2, v3, lo, true);
      hi = __builtin_amdgcn_cvt_pk_fp8_f32(v4, v5, hi, false);
      hi = __builtin_amdgcn_cvt_pk_fp8_f32(v6, v7, hi, true);
      uint2 o;
      o.x = (unsigned)lo;
      o.y = (unsigned)hi;
      *reinterpret_cast<uint2*>(&h8[(size_t)nd * 64 + f8]) = o;
    }
  }
}

// ---------------- fp8 gather body (agg1) ----------------
#define EDGE8(h8b, cc)                                                        \
  {                                                                           \
    uint2 w = *reinterpret_cast<const uint2*>(&h8b[(size_t)(cc) * 64 + f0]);  \
    f32x2 p0 = __builtin_amdgcn_cvt_pk_f32_fp8((int)w.x, false);              \
    f32x2 p1 = __builtin_amdgcn_cvt_pk_f32_fp8((int)w.x, true);               \
    f32x2 p2 = __builtin_amdgcn_cvt_pk_f32_fp8((int)w.y, false);              \
    f32x2 p3 = __builtin_amdgcn_cvt_pk_f32_fp8((int)w.y, true);               \
    acc0 += p0.x; acc1 += p0.y; acc2 += p1.x; acc3 += p1.y;                   \
    acc4 += p2.x; acc5 += p2.y; acc6 += p3.x; acc7 += p3.y;                   \
  }

// ---------------- bf16 gather body (agg2) ----------------
#define EDGEP(hbuf, cc)                                                       \
  {                                                                           \
    uint4 w = *reinterpret_cast<const uint4*>(&hbuf[(size_t)(cc) * 64 + f0]); \
    acc0 += bfu_lo(w.x); acc1 += bfu_hi(w.x);                                 \
    acc2 += bfu_lo(w.y); acc3 += bfu_hi(w.y);                                 \
    acc4 += bfu_lo(w.z); acc5 += bfu_hi(w.z);                                 \
    acc6 += bfu_lo(w.w); acc7 += bfu_hi(w.w);                                 \
  }

#define GATHER_LOOP(EDGE, hb, EV, ENDV)                                       \
  int e = EV;                                                                 \
  const int end = ENDV;                                                       \
  while (e < end && (e & 3)) { EDGE(hb, col[e]); ++e; }                       \
  for (; e + 8 <= end; e += 8) {                                              \
    int4 ca = *reinterpret_cast<const int4*>(&col[e]);                        \
    int4 cb = *reinterpret_cast<const int4*>(&col[e + 4]);                    \
    EDGE(hb, ca.x); EDGE(hb, ca.y); EDGE(hb, ca.z); EDGE(hb, ca.w);           \
    EDGE(hb, cb.x); EDGE(hb, cb.y); EDGE(hb, cb.z); EDGE(hb, cb.w);           \
  }                                                                           \
  for (; e + 4 <= end; e += 4) {                                              \
    int4 cc = *reinterpret_cast<const int4*>(&col[e]);                        \
    EDGE(hb, cc.x); EDGE(hb, cc.y); EDGE(hb, cc.z); EDGE(hb, cc.w);           \
  }                                                                           \
  for (; e < end; ++e) { EDGE(hb, col[e]); }

// ---------------- agg1 (fp8 gather) + bias/relu + GEMM2 fused ----------------
__global__ __launch_bounds__(256) void k_agg_gemm(
    const unsigned char* __restrict__ h8, const int* __restrict__ rowptr,
    const int* __restrict__ col, const float* __restrict__ dinv,
    const float* __restrict__ bias, const unsigned short* __restrict__ Wt2g,
    unsigned short* __restrict__ out) {
  const int t = threadIdx.x, lane = t & 63, wv = t >> 6;
  const int g = lane >> 3, f0 = (lane & 7) * 8;
  const int vbase = blockIdx.x * 32;
  const int v = vbase + wv * 8 + g;
  const int lrow = wv * 8 + g;

  __shared__ unsigned short h1s[32][72];  // pad: 144B stride

  if (v < N_NODES) {
    const float sv = dinv[v];
    float acc0 = 0, acc1 = 0, acc2 = 0, acc3 = 0, acc4 = 0, acc5 = 0, acc6 = 0, acc7 = 0;
    EDGE8(h8, v)  // self-loop term
    GATHER_LOOP(EDGE8, h8, rowptr[v], rowptr[v + 1])

    const float4 ba = *reinterpret_cast<const float4*>(&bias[f0]);
    const float4 bb = *reinterpret_cast<const float4*>(&bias[f0 + 4]);
    float v0 = fmaxf(fmaf(sv, acc0, ba.x), 0.0f);
    float v1 = fmaxf(fmaf(sv, acc1, ba.y), 0.0f);
    float v2 = fmaxf(fmaf(sv, acc2, ba.z), 0.0f);
    float v3 = fmaxf(fmaf(sv, acc3, ba.w), 0.0f);
    float v4 = fmaxf(fmaf(sv, acc4, bb.x), 0.0f);
    float v5 = fmaxf(fmaf(sv, acc5, bb.y), 0.0f);
    float v6 = fmaxf(fmaf(sv, acc6, bb.z), 0.0f);
    float v7 = fmaxf(fmaf(sv, acc7, bb.w), 0.0f);

    uint4 o;
    o.x = pack2(v0, v1); o.y = pack2(v2, v3);
    o.z = pack2(v4, v5); o.w = pack2(v6, v7);
    *reinterpret_cast<uint4*>(&h1s[lrow][f0]) = o;
  } else {
    uint4 z = {0, 0, 0, 0};
    *reinterpret_cast<uint4*>(&h1s[lrow][f0]) = z;
  }
  __syncthreads();

  // GEMM2: 32 nodes x 64 cols; wave wv owns cols [wv*16, wv*16+16); K=64.
  const int kh = (lane >> 4) * 8;
  f32x4 acc2r[2] = {};
#pragma unroll
  for (int rt = 0; rt < 2; ++rt) {
#pragma unroll
    for (int k0 = 0; k0 < 64; k0 += 32) {
      short8v a = *reinterpret_cast<const short8v*>(&h1s[rt * 16 + (lane & 15)][k0 + kh]);
      short8v b = *reinterpret_cast<const short8v*>(
          Wt2g + (size_t)(wv * 16 + (lane & 15)) * 64 + k0 + kh);
      acc2r[rt] = __builtin_amdgcn_mfma_f32_16x16x32_bf16(a, b, acc2r[rt], 0, 0, 0);
    }
  }
#pragma unroll
  for (int rt = 0; rt < 2; ++rt) {
#pragma unroll
    for (int j = 0; j < 4; ++j) {
      int vg = vbase + rt * 16 + (lane >> 4) * 4 + j;
      if (vg < N_NODES)
        out[(size_t)vg * 64 + wv * 16 + (lane & 15)] = f2bf(acc2r[rt][j] * dinv[vg]);
    }
  }
}

// ---------------- agg2 (bf16, plain adds) + classifier fused ----------------
__global__ __launch_bounds__(256) void k_agg_fin(
    const unsigned short* __restrict__ h, const int* __restrict__ rowptr,
    const int* __restrict__ col, const float* __restrict__ dinv,
    const float* __restrict__ bias, const float* __restrict__ Wc,
    const float* __restrict__ bc, float* __restrict__ out) {
  const int t = threadIdx.x, lane = t & 63;
  const int g = lane >> 3, f0 = (lane & 7) * 8;
  const int v = blockIdx.x * 32 + (t >> 6) * 8 + g;
  if (v >= N_NODES) return;

  uint4 sw = *reinterpret_cast<const uint4*>(&h[(size_t)v * 64 + f0]);
  float acc0 = bfu_lo(sw.x), acc1 = bfu_hi(sw.x);
  float acc2 = bfu_lo(sw.y), acc3 = bfu_hi(sw.y);
  float acc4 = bfu_lo(sw.z), acc5 = bfu_hi(sw.z);
  float acc6 = bfu_lo(sw.w), acc7 = bfu_hi(sw.w);
  GATHER_LOOP(EDGEP, h, rowptr[v], rowptr[v + 1])

  const float sv = dinv[v];
  const float4 ba = *reinterpret_cast<const float4*>(&bias[f0]);
  const float4 bb = *reinterpret_cast<const float4*>(&bias[f0 + 4]);
  const float4 wa = *reinterpret_cast<const float4*>(&Wc[f0]);
  const float4 wb = *reinterpret_cast<const float4*>(&Wc[f0 + 4]);
  float p = fmaxf(fmaf(sv, acc0, ba.x), 0.0f) * wa.x +
            fmaxf(fmaf(sv, acc1, ba.y), 0.0f) * wa.y +
            fmaxf(fmaf(sv, acc2, ba.z), 0.0f) * wa.z +
            fmaxf(fmaf(sv, acc3, ba.w), 0.0f) * wa.w +
            fmaxf(fmaf(sv, acc4, bb.x), 0.0f) * wb.x +
            fmaxf(fmaf(sv, acc5, bb.y), 0.0f) * wb.y +
            fmaxf(fmaf(sv, acc6, bb.z), 0.0f) * wb.z +
            fmaxf(fmaf(sv, acc7, bb.w), 0.0f) * wb.w;
  p += __shfl_xor(p, 1);
  p += __shfl_xor(p, 2);
  p += __shfl_xor(p, 4);
  if ((lane & 7) == 0) out[v] = 1.0f / (1.0f + expf(-(p + bc[0])));
}

extern "C" void kernel_launch(void* const* d_in, const int* in_sizes, int n_in,
                              void* d_out, int out_size, void* d_ws, size_t ws_size,
                              hipStream_t stream) {
  const float* x  = (const float*)d_in[0];
  const int*   ei = (const int*)d_in[1];
  const float* W1 = (const float*)d_in[2];
  const float* b1 = (const float*)d_in[3];
  const float* W2 = (const float*)d_in[4];
  const float* b2 = (const float*)d_in[5];
  const float* Wc = (const float*)d_in[6];
  const float* bc = (const float*)d_in[7];
  float* out = (float*)d_out;

  const int* src = ei;
  const int* dst = ei + N_EDGES;

  // workspace layout (u32 units)
  unsigned* w = (unsigned*)d_ws;
  int*   bcur   = (int*)(w + 0);            // 256
  int*   rowptr = (int*)(w + 256);          // 50432 (needs 50001)
  int*   colidx = (int*)(w + 50688);        // 800000
  unsigned* ebuf = w + 850688;              // 196*8192 = 1605632
  float* dinv   = (float*)(w + 2456320);    // 50176
  unsigned short* Wt1g = (unsigned short*)(w + 2506496);  // 16384 ush
  unsigned short* Wt2g = (unsigned short*)(w + 2514688);  // 4096 ush
  unsigned short* A_bf = (unsigned short*)(w + 2516736);  // 3.2M ush (x@W1, unscaled)
  unsigned short* B_bf = (unsigned short*)(w + 4116736);  // 3.2M ush (h2', scaled)
  unsigned char*  A_f8 = (unsigned char*)(w + 5716736);   // 3.2M bytes (h1', fp8 scaled)

  k_prep<<<3, 256, 0, stream>>>(bcur, W1, W2, Wt1g, Wt2g);
  // GEMM1 (unscaled) runs concurrently with edge split in one dispatch
  k_g1split<<<NGB + NCH, 256, 0, stream>>>(x, Wt1g, A_bf, src, dst, bcur, ebuf);
  // CSR build + dinv + fp8 h1' emission (L2-resident 3.2MB rows for agg1)
  k_bucket<<<NBKT, 256, 0, stream>>>(ebuf, bcur, rowptr, colidx, dinv, A_bf, A_f8);

  const int NAB = (N_NODES + 31) / 32;  // 1563
  k_agg_gemm<<<NAB, 256, 0, stream>>>(A_f8, rowptr, colidx, dinv, b1, Wt2g, B_bf);
  k_agg_fin<<<NAB, 256, 0, stream>>>(B_bf, rowptr, colidx, dinv, b2, Wc, bc, out);
}

// Round 16
// 86.350 us; speedup vs baseline: 1.4586x; 1.0401x over previous
//
#include <hip/hip_runtime.h>
#include <math.h>

#define N_NODES 50000
#define N_EDGES 800000
#define IN_DIM 256
#define HID 64
#define BKT 256
#define NBKT ((N_NODES + BKT - 1) / BKT)          // 196
#define CAP 8192                                  // ebuf slots per bucket (max real ~4400)
#define SEGC 5120                                 // LDS-cached entries per bucket
#define CHUNK 4096
#define NCH ((N_EDGES + CHUNK - 1) / CHUNK)       // 196
#define NGB ((N_NODES + 63) / 64)                 // 782

typedef short short8v __attribute__((ext_vector_type(8)));
typedef float f32x4 __attribute__((ext_vector_type(4)));
typedef float f32x2 __attribute__((ext_vector_type(2)));
typedef unsigned uint4v __attribute__((ext_vector_type(4)));

__device__ __forceinline__ unsigned short f2bf(float f) {
  unsigned u = __builtin_bit_cast(unsigned, f);
  u += 0x7FFFu + ((u >> 16) & 1u);  // RNE
  return (unsigned short)(u >> 16);
}
__device__ __forceinline__ unsigned pack2(float a, float b) {
  return (unsigned)f2bf(a) | ((unsigned)f2bf(b) << 16);
}
__device__ __forceinline__ float bfu_lo(unsigned u) {
  return __builtin_bit_cast(float, u << 16);
}
__device__ __forceinline__ float bfu_hi(unsigned u) {
  return __builtin_bit_cast(float, u & 0xFFFF0000u);
}
__device__ __forceinline__ unsigned char f2fp8(float f) {
  return (unsigned char)(__builtin_amdgcn_cvt_pk_fp8_f32(f, f, 0, false) & 0xFF);
}

// ---------------- prep: zero bcur + convert/transpose weights ----------------
__global__ void k_prep(int* __restrict__ bcur, const float* __restrict__ W1,
                       const float* __restrict__ W2, unsigned short* __restrict__ Wt1,
                       unsigned short* __restrict__ Wt2) {
  const int t = threadIdx.x;
  if (blockIdx.x == 0) {
    bcur[t] = 0;
  } else if (blockIdx.x == 1) {
    for (int j = 0; j < 64; ++j) {
      int lin = j * 256 + t;
      int k = lin >> 6, c = lin & 63;
      Wt1[c * 256 + k] = f2bf(W1[lin]);
    }
  } else {
    for (int j = 0; j < 16; ++j) {
      int lin = j * 256 + t;
      int k = lin >> 6, c = lin & 63;
      Wt2[c * 64 + k] = f2bf(W2[lin]);
    }
  }
}

// ---------------- fused: GEMM1 (blocks 0..NGB) || split (blocks NGB..) ----------------
// GEMM1: outA[r][c] = bf16( sum_k X[r][k]*W1[k][c] )  -- UNSCALED
__global__ __launch_bounds__(256) void k_g1split(
    const float* __restrict__ X, const unsigned short* __restrict__ Wt1g,
    unsigned short* __restrict__ outA, const int* __restrict__ src,
    const int* __restrict__ dst, int* __restrict__ bcur, unsigned* __restrict__ ebuf) {
  __shared__ unsigned short Wl[64][IN_DIM + 8];  // gemm1 branch (33.8KB)
  __shared__ int cnt[NBKT];                      // split branch
  __shared__ int cur[NBKT];
  const int t = threadIdx.x;
  if (blockIdx.x < NGB) {
    const int lane = t & 63, wv = t >> 6;
#pragma unroll
    for (int j = 0; j < 8; ++j) {
      int grp = j * 256 + t;
      int r = grp >> 5, c = (grp & 31) * 8;
      *reinterpret_cast<short8v*>(&Wl[r][c]) =
          *reinterpret_cast<const short8v*>(&Wt1g[r * IN_DIM + c]);
    }
    const int row0 = blockIdx.x * 64;
    int r = row0 + wv * 16 + (lane & 15);
    if (r > N_NODES - 1) r = N_NODES - 1;  // clamp (stores guarded)
    const int kh = (lane >> 4) * 8;

    uint4v ap[8];
#pragma unroll
    for (int k0 = 0; k0 < 8; ++k0) {
      const float* Xp = X + (size_t)r * IN_DIM + k0 * 32 + kh;
      const float4 x0 = *reinterpret_cast<const float4*>(Xp);
      const float4 x1 = *reinterpret_cast<const float4*>(Xp + 4);
      uint4v p;
      p.x = pack2(x0.x, x0.y); p.y = pack2(x0.z, x0.w);
      p.z = pack2(x1.x, x1.y); p.w = pack2(x1.z, x1.w);
      ap[k0] = p;
    }
    __syncthreads();

    f32x4 acc[4] = {};
#pragma unroll
    for (int k0 = 0; k0 < 8; ++k0) {
      short8v a = __builtin_bit_cast(short8v, ap[k0]);
#pragma unroll
      for (int n = 0; n < 4; ++n) {
        short8v b = *reinterpret_cast<const short8v*>(&Wl[n * 16 + (lane & 15)][k0 * 32 + kh]);
        acc[n] = __builtin_amdgcn_mfma_f32_16x16x32_bf16(a, b, acc[n], 0, 0, 0);
      }
    }

    const int r0 = row0 + wv * 16;
#pragma unroll
    for (int j = 0; j < 4; ++j) {
      int rr = r0 + (lane >> 4) * 4 + j;
      if (rr < N_NODES) {
#pragma unroll
        for (int n = 0; n < 4; ++n)
          outA[(size_t)rr * 64 + n * 16 + (lane & 15)] = f2bf(acc[n][j]);
      }
    }
  } else {
    // ---- split: edges -> padded bucket regions (packed u32: src<<8 | dstLocal) ----
    for (int i = t; i < NBKT; i += 256) cnt[i] = 0;
    __syncthreads();
    const int base = (blockIdx.x - NGB) * CHUNK;
#pragma unroll
    for (int i = 0; i < CHUNK / 256; ++i) {
      int e = base + i * 256 + t;
      if (e < N_EDGES) atomicAdd(&cnt[dst[e] >> 8], 1);
    }
    __syncthreads();
    for (int i = t; i < NBKT; i += 256) {
      int c = cnt[i];
      cur[i] = c ? (i * CAP + atomicAdd(&bcur[i], c)) : 0;
    }
    __syncthreads();
#pragma unroll
    for (int i = 0; i < CHUNK / 256; ++i) {
      int e = base + i * 256 + t;
      if (e < N_EDGES) {
        int d = dst[e];
        int p = atomicAdd(&cur[d >> 8], 1);
        ebuf[p] = ((unsigned)src[e] << 8) | (unsigned)(d & 255);
      }
    }
  }
}

// ---------------- bucket: fine CSR (ushort col) + dinv + scaled fp8 h1' ----------------
__global__ void k_bucket(const unsigned* __restrict__ ebuf, const int* __restrict__ bcur,
                         int* __restrict__ rowptr, unsigned short* __restrict__ colidx,
                         float* __restrict__ dinv, const unsigned short* __restrict__ hbf,
                         unsigned char* __restrict__ h8) {
  __shared__ int sA[256];
  __shared__ int sB[256];
  __shared__ float sD[256];
  __shared__ unsigned seg[SEGC];  // 20KB
  const int b = blockIdx.x, t = threadIdx.x;

  const int cntb = bcur[b];
  const int sbeg = b * CAP;
  const int cached = cntb < SEGC ? cntb : SEGC;

  // issue LDS cache fill first; latency hides under the prefix scan below
  for (int i = t; i < cached; i += 256) seg[i] = ebuf[sbeg + i];

  // global colidx base via redundant scan of bucket counts
  sA[t] = (t < NBKT) ? bcur[t] : 0;
  __syncthreads();
  for (int d = 1; d < 256; d <<= 1) {
    int v = sA[t];
    int a = (t >= d) ? sA[t - d] : 0;
    __syncthreads();
    sA[t] = v + a;
    __syncthreads();
  }
  const int prefix = (b == 0) ? 0 : sA[b - 1];
  __syncthreads();

  // per-node degree within bucket (from LDS segment)
  sA[t] = 0;
  __syncthreads();
  for (int i = t; i < cached; i += 256) atomicAdd(&sA[seg[i] & 255], 1);
  for (int i = SEGC + t; i < cntb; i += 256) atomicAdd(&sA[ebuf[sbeg + i] & 255], 1);
  __syncthreads();
  const int myc = sA[t];
  sB[t] = myc;
  __syncthreads();
  for (int d = 1; d < 256; d <<= 1) {
    int v = sB[t];
    int a = (t >= d) ? sB[t - d] : 0;
    __syncthreads();
    sB[t] = v + a;
    __syncthreads();
  }
  const int node = b * BKT + t;
  const bool valid = node < N_NODES;
  const int ex = prefix + sB[t] - myc;
  const float dv = rsqrtf((float)(myc + 1));
  sD[t] = dv;
  if (valid) {
    rowptr[node] = ex;
    dinv[node] = dv;
    if (node == N_NODES - 1) rowptr[N_NODES] = N_EDGES;
  }
  __syncthreads();
  sB[t] = ex;  // per-node cursor
  __syncthreads();
  for (int i = t; i < cached; i += 256) {
    unsigned p = seg[i];
    int pos = atomicAdd(&sB[p & 255], 1);
    colidx[pos] = (unsigned short)((p >> 8) & 0xFFFFu);
  }
  for (int i = SEGC + t; i < cntb; i += 256) {
    unsigned p = ebuf[sbeg + i];
    int pos = atomicAdd(&sB[p & 255], 1);
    colidx[pos] = (unsigned short)((p >> 8) & 0xFFFFu);
  }

  // emit h1'[v] = fp8_e4m3( dinv[v] * h[v] ) -- 64B rows, L2-resident for agg1
  const int rsub = t >> 3, f8 = (t & 7) * 8;
#pragma unroll
  for (int g = 0; g < 8; ++g) {
    int lr = g * 32 + rsub;
    int nd = b * BKT + lr;
    if (nd < N_NODES) {
      float s = sD[lr];
      const unsigned short* hp = &hbf[(size_t)nd * 64 + f8];
      uint4 hv = *reinterpret_cast<const uint4*>(hp);
      float v0 = s * bfu_lo(hv.x), v1 = s * bfu_hi(hv.x);
      float v2 = s * bfu_lo(hv.y), v3 = s * bfu_hi(hv.y);
      float v4 = s * bfu_lo(hv.z), v5 = s * bfu_hi(hv.z);
      float v6 = s * bfu_lo(hv.w), v7 = s * bfu_hi(hv.w);
      int lo = 0, hi = 0;
      lo = __builtin_amdgcn_cvt_pk_fp8_f32(v0, v1, lo, false);
      lo = __builtin_amdgcn_cvt_pk_fp8_f32(v2, v3, lo, true);
      hi = __builtin_amdgcn_cvt_pk_fp8_f32(v4, v5, hi, false);
      hi = __builtin_amdgcn_cvt_pk_fp8_f32(v6, v7, hi, true);
      uint2 o;
      o.x = (unsigned)lo;
      o.y = (unsigned)hi;
      *reinterpret_cast<uint2*>(&h8[(size_t)nd * 64 + f8]) = o;
    }
  }
}

// ---------------- fp8 gather body ----------------
#define EDGE8(h8b, cc)                                                        \
  {                                                                           \
    uint2 w = *reinterpret_cast<const uint2*>(&h8b[(size_t)(cc) * 64 + f0]);  \
    f32x2 p0 = __builtin_amdgcn_cvt_pk_f32_fp8((int)w.x, false);              \
    f32x2 p1 = __builtin_amdgcn_cvt_pk_f32_fp8((int)w.x, true);               \
    f32x2 p2 = __builtin_amdgcn_cvt_pk_f32_fp8((int)w.y, false);              \
    f32x2 p3 = __builtin_amdgcn_cvt_pk_f32_fp8((int)w.y, true);               \
    acc0 += p0.x; acc1 += p0.y; acc2 += p1.x; acc3 += p1.y;                   \
    acc4 += p2.x; acc5 += p2.y; acc6 += p3.x; acc7 += p3.y;                   \
  }

// ushort col stream: 8 edges per 16B load
#define GATHER_F8(h8b)                                                        \
  int e = rowptr[v];                                                          \
  const int end = rowptr[v + 1];                                              \
  while (e < end && (e & 7)) { EDGE8(h8b, col[e]); ++e; }                     \
  for (; e + 8 <= end; e += 8) {                                              \
    short8v cw = *reinterpret_cast<const short8v*>(&col[e]);                  \
    EDGE8(h8b, (unsigned short)cw[0]); EDGE8(h8b, (unsigned short)cw[1]);     \
    EDGE8(h8b, (unsigned short)cw[2]); EDGE8(h8b, (unsigned short)cw[3]);     \
    EDGE8(h8b, (unsigned short)cw[4]); EDGE8(h8b, (unsigned short)cw[5]);     \
    EDGE8(h8b, (unsigned short)cw[6]); EDGE8(h8b, (unsigned short)cw[7]);     \
  }                                                                           \
  for (; e < end; ++e) { EDGE8(h8b, col[e]); }

// ---------------- agg1 (fp8 gather) + bias/relu + GEMM2 + fp8 h2' out ----------------
__global__ __launch_bounds__(256) void k_agg_gemm(
    const unsigned char* __restrict__ h8, const int* __restrict__ rowptr,
    const unsigned short* __restrict__ col, const float* __restrict__ dinv,
    const float* __restrict__ bias, const unsigned short* __restrict__ Wt2g,
    unsigned char* __restrict__ out8) {
  const int t = threadIdx.x, lane = t & 63, wv = t >> 6;
  const int g = lane >> 3, f0 = (lane & 7) * 8;
  const int vbase = blockIdx.x * 32;
  const int v = vbase + wv * 8 + g;
  const int lrow = wv * 8 + g;

  __shared__ unsigned short h1s[32][72];  // pad: 144B stride

  if (v < N_NODES) {
    const float sv = dinv[v];
    float acc0 = 0, acc1 = 0, acc2 = 0, acc3 = 0, acc4 = 0, acc5 = 0, acc6 = 0, acc7 = 0;
    EDGE8(h8, v)  // self-loop term
    GATHER_F8(h8)

    const float4 ba = *reinterpret_cast<const float4*>(&bias[f0]);
    const float4 bb = *reinterpret_cast<const float4*>(&bias[f0 + 4]);
    float v0 = fmaxf(fmaf(sv, acc0, ba.x), 0.0f);
    float v1 = fmaxf(fmaf(sv, acc1, ba.y), 0.0f);
    float v2 = fmaxf(fmaf(sv, acc2, ba.z), 0.0f);
    float v3 = fmaxf(fmaf(sv, acc3, ba.w), 0.0f);
    float v4 = fmaxf(fmaf(sv, acc4, bb.x), 0.0f);
    float v5 = fmaxf(fmaf(sv, acc5, bb.y), 0.0f);
    float v6 = fmaxf(fmaf(sv, acc6, bb.z), 0.0f);
    float v7 = fmaxf(fmaf(sv, acc7, bb.w), 0.0f);

    uint4 o;
    o.x = pack2(v0, v1); o.y = pack2(v2, v3);
    o.z = pack2(v4, v5); o.w = pack2(v6, v7);
    *reinterpret_cast<uint4*>(&h1s[lrow][f0]) = o;
  } else {
    uint4 z = {0, 0, 0, 0};
    *reinterpret_cast<uint4*>(&h1s[lrow][f0]) = z;
  }
  __syncthreads();

  // GEMM2: 32 nodes x 64 cols; wave wv owns cols [wv*16, wv*16+16); K=64.
  const int kh = (lane >> 4) * 8;
  f32x4 acc2r[2] = {};
#pragma unroll
  for (int rt = 0; rt < 2; ++rt) {
#pragma unroll
    for (int k0 = 0; k0 < 64; k0 += 32) {
      short8v a = *reinterpret_cast<const short8v*>(&h1s[rt * 16 + (lane & 15)][k0 + kh]);
      short8v b = *reinterpret_cast<const short8v*>(
          Wt2g + (size_t)(wv * 16 + (lane & 15)) * 64 + k0 + kh);
      acc2r[rt] = __builtin_amdgcn_mfma_f32_16x16x32_bf16(a, b, acc2r[rt], 0, 0, 0);
    }
  }
  // epilogue: h2'[r][c] = fp8( dinv[r] * acc )  (64B rows for agg2)
#pragma unroll
  for (int rt = 0; rt < 2; ++rt) {
#pragma unroll
    for (int j = 0; j < 4; ++j) {
      int vg = vbase + rt * 16 + (lane >> 4) * 4 + j;
      if (vg < N_NODES)
        out8[(size_t)vg * 64 + wv * 16 + (lane & 15)] = f2fp8(acc2r[rt][j] * dinv[vg]);
    }
  }
}

// ---------------- agg2 (fp8 gather) + classifier fused ----------------
__global__ __launch_bounds__(256) void k_agg_fin(
    const unsigned char* __restrict__ h8, const int* __restrict__ rowptr,
    const unsigned short* __restrict__ col, const float* __restrict__ dinv,
    const float* __restrict__ bias, const float* __restrict__ Wc,
    const float* __restrict__ bc, float* __restrict__ out) {
  const int t = threadIdx.x, lane = t & 63;
  const int g = lane >> 3, f0 = (lane & 7) * 8;
  const int v = blockIdx.x * 32 + (t >> 6) * 8 + g;
  if (v >= N_NODES) return;

  float acc0 = 0, acc1 = 0, acc2 = 0, acc3 = 0, acc4 = 0, acc5 = 0, acc6 = 0, acc7 = 0;
  EDGE8(h8, v)  // self-loop term
  GATHER_F8(h8)

  const float sv = dinv[v];
  const float4 ba = *reinterpret_cast<const float4*>(&bias[f0]);
  const float4 bb = *reinterpret_cast<const float4*>(&bias[f0 + 4]);
  const float4 wa = *reinterpret_cast<const float4*>(&Wc[f0]);
  const float4 wb = *reinterpret_cast<const float4*>(&Wc[f0 + 4]);
  float p = fmaxf(fmaf(sv, acc0, ba.x), 0.0f) * wa.x +
            fmaxf(fmaf(sv, acc1, ba.y), 0.0f) * wa.y +
            fmaxf(fmaf(sv, acc2, ba.z), 0.0f) * wa.z +
            fmaxf(fmaf(sv, acc3, ba.w), 0.0f) * wa.w +
            fmaxf(fmaf(sv, acc4, bb.x), 0.0f) * wb.x +
            fmaxf(fmaf(sv, acc5, bb.y), 0.0f) * wb.y +
            fmaxf(fmaf(sv, acc6, bb.z), 0.0f) * wb.z +
            fmaxf(fmaf(sv, acc7, bb.w), 0.0f) * wb.w;
  p += __shfl_xor(p, 1);
  p += __shfl_xor(p, 2);
  p += __shfl_xor(p, 4);
  if ((lane & 7) == 0) out[v] = 1.0f / (1.0f + expf(-(p + bc[0])));
}

extern "C" void kernel_launch(void* const* d_in, const int* in_sizes, int n_in,
                              void* d_out, int out_size, void* d_ws, size_t ws_size,
                              hipStream_t stream) {
  const float* x  = (const float*)d_in[0];
  const int*   ei = (const int*)d_in[1];
  const float* W1 = (const float*)d_in[2];
  const float* b1 = (const float*)d_in[3];
  const float* W2 = (const float*)d_in[4];
  const float* b2 = (const float*)d_in[5];
  const float* Wc = (const float*)d_in[6];
  const float* bc = (const float*)d_in[7];
  float* out = (float*)d_out;

  const int* src = ei;
  const int* dst = ei + N_EDGES;

  // workspace layout (u32 units)
  unsigned* w = (unsigned*)d_ws;
  int*   bcur   = (int*)(w + 0);                          // 256
  int*   rowptr = (int*)(w + 256);                        // 50432 (needs 50001)
  unsigned short* colidx = (unsigned short*)(w + 50688);  // 800000 ush = 400000 u32
  unsigned* ebuf = w + 450688;                            // 196*8192 = 1605632
  float* dinv   = (float*)(w + 2056320);                  // 50176
  unsigned short* Wt1g = (unsigned short*)(w + 2106496);  // 16384 ush
  unsigned short* Wt2g = (unsigned short*)(w + 2114688);  // 4096 ush
  unsigned short* A_bf = (unsigned short*)(w + 2116736);  // 3.2M ush (x@W1, unscaled)
  unsigned char*  A_f8 = (unsigned char*)(w + 3716736);   // 3.2M B (h1', fp8 scaled)
  unsigned char*  B_f8 = (unsigned char*)(w + 4516736);   // 3.2M B (h2', fp8 scaled)

  k_prep<<<3, 256, 0, stream>>>(bcur, W1, W2, Wt1g, Wt2g);
  // GEMM1 (unscaled) runs concurrently with edge split in one dispatch
  k_g1split<<<NGB + NCH, 256, 0, stream>>>(x, Wt1g, A_bf, src, dst, bcur, ebuf);
  // CSR build (ushort col) + dinv + fp8 h1' emission
  k_bucket<<<NBKT, 256, 0, stream>>>(ebuf, bcur, rowptr, colidx, dinv, A_bf, A_f8);

  const int NAB = (N_NODES + 31) / 32;  // 1563
  k_agg_gemm<<<NAB, 256, 0, stream>>>(A_f8, rowptr, colidx, dinv, b1, Wt2g, B_f8);
  k_agg_fin<<<NAB, 256, 0, stream>>>(B_f8, rowptr, colidx, dinv, b2, Wc, bc, out);
}

// Round 17
// 86.170 us; speedup vs baseline: 1.4616x; 1.0021x over previous
//
#include <hip/hip_runtime.h>
#include <math.h>

#define N_NODES 50000
#define N_EDGES 800000
#define IN_DIM 256
#define HID 64
#define BKT 256
#define NBKT ((N_NODES + BKT - 1) / BKT)          // 196
#define CAP 8192                                  // ebuf slots per bucket (max real ~4400)
#define SEGC 5120                                 // LDS-cached entries per bucket
#define CHUNK 4096
#define NCH ((N_EDGES + CHUNK - 1) / CHUNK)       // 196
#define NGB ((N_NODES + 63) / 64)                 // 782

typedef short short8v __attribute__((ext_vector_type(8)));
typedef float f32x4 __attribute__((ext_vector_type(4)));
typedef float f32x2 __attribute__((ext_vector_type(2)));
typedef unsigned uint4v __attribute__((ext_vector_type(4)));

__device__ __forceinline__ unsigned short f2bf(float f) {
  unsigned u = __builtin_bit_cast(unsigned, f);
  u += 0x7FFFu + ((u >> 16) & 1u);  // RNE
  return (unsigned short)(u >> 16);
}
__device__ __forceinline__ unsigned pack2(float a, float b) {
  return (unsigned)f2bf(a) | ((unsigned)f2bf(b) << 16);
}
__device__ __forceinline__ float bfu_lo(unsigned u) {
  return __builtin_bit_cast(float, u << 16);
}
__device__ __forceinline__ float bfu_hi(unsigned u) {
  return __builtin_bit_cast(float, u & 0xFFFF0000u);
}
__device__ __forceinline__ unsigned char f2fp8(float f) {
  return (unsigned char)(__builtin_amdgcn_cvt_pk_fp8_f32(f, f, 0, false) & 0xFF);
}

// ---------------- prep: zero bcur + convert/transpose weights ----------------
__global__ void k_prep(int* __restrict__ bcur, const float* __restrict__ W1,
                       const float* __restrict__ W2, unsigned short* __restrict__ Wt1,
                       unsigned short* __restrict__ Wt2) {
  const int t = threadIdx.x;
  if (blockIdx.x == 0) {
    bcur[t] = 0;
  } else if (blockIdx.x == 1) {
    for (int j = 0; j < 64; ++j) {
      int lin = j * 256 + t;
      int k = lin >> 6, c = lin & 63;
      Wt1[c * 256 + k] = f2bf(W1[lin]);
    }
  } else {
    for (int j = 0; j < 16; ++j) {
      int lin = j * 256 + t;
      int k = lin >> 6, c = lin & 63;
      Wt2[c * 64 + k] = f2bf(W2[lin]);
    }
  }
}

// ---------------- fused: GEMM1 (blocks 0..NGB) || split (blocks NGB..) ----------------
// GEMM1: outA[r][c] = bf16( sum_k X[r][k]*W1[k][c] )  -- UNSCALED
// split: LDS-staged dense bucket sort (entry = b<<24 | src<<8 | dstLocal)
__global__ __launch_bounds__(256) void k_g1split(
    const float* __restrict__ X, const unsigned short* __restrict__ Wt1g,
    unsigned short* __restrict__ outA, const int* __restrict__ src,
    const int* __restrict__ dst, int* __restrict__ bcur, unsigned* __restrict__ ebuf) {
  __shared__ __align__(16) unsigned char smem[(64 * (IN_DIM + 8)) * 2];  // 33.8KB overlay
  const int t = threadIdx.x;
  if (blockIdx.x < NGB) {
    unsigned short(*Wl)[IN_DIM + 8] = (unsigned short(*)[IN_DIM + 8])smem;
    const int lane = t & 63, wv = t >> 6;
#pragma unroll
    for (int j = 0; j < 8; ++j) {
      int grp = j * 256 + t;
      int r = grp >> 5, c = (grp & 31) * 8;
      *reinterpret_cast<short8v*>(&Wl[r][c]) =
          *reinterpret_cast<const short8v*>(&Wt1g[r * IN_DIM + c]);
    }
    const int row0 = blockIdx.x * 64;
    int r = row0 + wv * 16 + (lane & 15);
    if (r > N_NODES - 1) r = N_NODES - 1;  // clamp (stores guarded)
    const int kh = (lane >> 4) * 8;

    uint4v ap[8];
#pragma unroll
    for (int k0 = 0; k0 < 8; ++k0) {
      const float* Xp = X + (size_t)r * IN_DIM + k0 * 32 + kh;
      const float4 x0 = *reinterpret_cast<const float4*>(Xp);
      const float4 x1 = *reinterpret_cast<const float4*>(Xp + 4);
      uint4v p;
      p.x = pack2(x0.x, x0.y); p.y = pack2(x0.z, x0.w);
      p.z = pack2(x1.x, x1.y); p.w = pack2(x1.z, x1.w);
      ap[k0] = p;
    }
    __syncthreads();

    f32x4 acc[4] = {};
#pragma unroll
    for (int k0 = 0; k0 < 8; ++k0) {
      short8v a = __builtin_bit_cast(short8v, ap[k0]);
#pragma unroll
      for (int n = 0; n < 4; ++n) {
        short8v b = *reinterpret_cast<const short8v*>(&Wl[n * 16 + (lane & 15)][k0 * 32 + kh]);
        acc[n] = __builtin_amdgcn_mfma_f32_16x16x32_bf16(a, b, acc[n], 0, 0, 0);
      }
    }

    const int r0 = row0 + wv * 16;
#pragma unroll
    for (int j = 0; j < 4; ++j) {
      int rr = r0 + (lane >> 4) * 4 + j;
      if (rr < N_NODES) {
#pragma unroll
        for (int n = 0; n < 4; ++n)
          outA[(size_t)rr * 64 + n * 16 + (lane & 15)] = f2bf(acc[n][j]);
      }
    }
  } else {
    // ---- split: LDS-staged bucket sort, dense write-out ----
    unsigned* stage = (unsigned*)smem;              // 4096 u32 = 16KB
    int* cnt   = (int*)(smem + 16384);              // 256
    int* off   = (int*)(smem + 17408);              // 256
    int* gbase = (int*)(smem + 18432);              // 256
    int* lcur  = (int*)(smem + 19456);              // 256
    const int base = (blockIdx.x - NGB) * CHUNK;
    const int valid = min(CHUNK, N_EDGES - base);

    cnt[t] = 0;
    __syncthreads();
    // pass 1: count buckets
#pragma unroll
    for (int i = 0; i < CHUNK / 256; ++i) {
      int e = base + i * 256 + t;
      if (e < N_EDGES) atomicAdd(&cnt[dst[e] >> 8], 1);
    }
    __syncthreads();
    // scan -> off (exclusive within chunk); reserve global runs
    {
      int c = cnt[t];
      off[t] = c;
      __syncthreads();
      for (int d = 1; d < 256; d <<= 1) {
        int v = off[t];
        int a = (t >= d) ? off[t - d] : 0;
        __syncthreads();
        off[t] = v + a;
        __syncthreads();
      }
      int ex = off[t] - c;
      off[t] = ex;
      lcur[t] = ex;
      gbase[t] = (t < NBKT && c) ? (t * CAP + atomicAdd(&bcur[t], c)) : 0;
    }
    __syncthreads();
    // pass 2: scatter into LDS stage (bucket-sorted)
#pragma unroll
    for (int i = 0; i < CHUNK / 256; ++i) {
      int e = base + i * 256 + t;
      if (e < N_EDGES) {
        int d = dst[e];
        int b = d >> 8;
        int p = atomicAdd(&lcur[b], 1);
        stage[p] = ((unsigned)b << 24) | ((unsigned)src[e] << 8) | (unsigned)(d & 255);
      }
    }
    __syncthreads();
    // pass 3: dense copy-out (consecutive lanes -> consecutive addresses per run)
    for (int i = t; i < valid; i += 256) {
      unsigned u = stage[i];
      int b = u >> 24;
      ebuf[gbase[b] + (i - off[b])] = u;
    }
  }
}

// ---------------- bucket: fine CSR (ushort col) + dinv + scaled fp8 h1' ----------------
__global__ void k_bucket(const unsigned* __restrict__ ebuf, const int* __restrict__ bcur,
                         int* __restrict__ rowptr, unsigned short* __restrict__ colidx,
                         float* __restrict__ dinv, const unsigned short* __restrict__ hbf,
                         unsigned char* __restrict__ h8) {
  __shared__ int sA[256];
  __shared__ int sB[256];
  __shared__ float sD[256];
  __shared__ unsigned seg[SEGC];  // 20KB
  const int b = blockIdx.x, t = threadIdx.x;

  const int cntb = bcur[b];
  const int sbeg = b * CAP;
  const int cached = cntb < SEGC ? cntb : SEGC;

  // issue LDS cache fill first; latency hides under the prefix scan below
  for (int i = t; i < cached; i += 256) seg[i] = ebuf[sbeg + i];

  // global colidx base via redundant scan of bucket counts
  sA[t] = (t < NBKT) ? bcur[t] : 0;
  __syncthreads();
  for (int d = 1; d < 256; d <<= 1) {
    int v = sA[t];
    int a = (t >= d) ? sA[t - d] : 0;
    __syncthreads();
    sA[t] = v + a;
    __syncthreads();
  }
  const int prefix = (b == 0) ? 0 : sA[b - 1];
  __syncthreads();

  // per-node degree within bucket (from LDS segment)
  sA[t] = 0;
  __syncthreads();
  for (int i = t; i < cached; i += 256) atomicAdd(&sA[seg[i] & 255], 1);
  for (int i = SEGC + t; i < cntb; i += 256) atomicAdd(&sA[ebuf[sbeg + i] & 255], 1);
  __syncthreads();
  const int myc = sA[t];
  sB[t] = myc;
  __syncthreads();
  for (int d = 1; d < 256; d <<= 1) {
    int v = sB[t];
    int a = (t >= d) ? sB[t - d] : 0;
    __syncthreads();
    sB[t] = v + a;
    __syncthreads();
  }
  const int node = b * BKT + t;
  const bool valid = node < N_NODES;
  const int ex = prefix + sB[t] - myc;
  const float dv = rsqrtf((float)(myc + 1));
  sD[t] = dv;
  if (valid) {
    rowptr[node] = ex;
    dinv[node] = dv;
    if (node == N_NODES - 1) rowptr[N_NODES] = N_EDGES;
  }
  __syncthreads();
  sB[t] = ex;  // per-node cursor
  __syncthreads();
  for (int i = t; i < cached; i += 256) {
    unsigned p = seg[i];
    int pos = atomicAdd(&sB[p & 255], 1);
    colidx[pos] = (unsigned short)((p >> 8) & 0xFFFFu);
  }
  for (int i = SEGC + t; i < cntb; i += 256) {
    unsigned p = ebuf[sbeg + i];
    int pos = atomicAdd(&sB[p & 255], 1);
    colidx[pos] = (unsigned short)((p >> 8) & 0xFFFFu);
  }

  // emit h1'[v] = fp8_e4m3( dinv[v] * h[v] ) -- 64B rows, L2-resident for agg1
  const int rsub = t >> 3, f8 = (t & 7) * 8;
#pragma unroll
  for (int g = 0; g < 8; ++g) {
    int lr = g * 32 + rsub;
    int nd = b * BKT + lr;
    if (nd < N_NODES) {
      float s = sD[lr];
      const unsigned short* hp = &hbf[(size_t)nd * 64 + f8];
      uint4 hv = *reinterpret_cast<const uint4*>(hp);
      float v0 = s * bfu_lo(hv.x), v1 = s * bfu_hi(hv.x);
      float v2 = s * bfu_lo(hv.y), v3 = s * bfu_hi(hv.y);
      float v4 = s * bfu_lo(hv.z), v5 = s * bfu_hi(hv.z);
      float v6 = s * bfu_lo(hv.w), v7 = s * bfu_hi(hv.w);
      int lo = 0, hi = 0;
      lo = __builtin_amdgcn_cvt_pk_fp8_f32(v0, v1, lo, false);
      lo = __builtin_amdgcn_cvt_pk_fp8_f32(v2, v3, lo, true);
      hi = __builtin_amdgcn_cvt_pk_fp8_f32(v4, v5, hi, false);
      hi = __builtin_amdgcn_cvt_pk_fp8_f32(v6, v7, hi, true);
      uint2 o;
      o.x = (unsigned)lo;
      o.y = (unsigned)hi;
      *reinterpret_cast<uint2*>(&h8[(size_t)nd * 64 + f8]) = o;
    }
  }
}

// ---------------- fp8 gather body ----------------
#define EDGE8(h8b, cc)                                                        \
  {                                                                           \
    uint2 w = *reinterpret_cast<const uint2*>(&h8b[(size_t)(cc) * 64 + f0]);  \
    f32x2 p0 = __builtin_amdgcn_cvt_pk_f32_fp8((int)w.x, false);              \
    f32x2 p1 = __builtin_amdgcn_cvt_pk_f32_fp8((int)w.x, true);               \
    f32x2 p2 = __builtin_amdgcn_cvt_pk_f32_fp8((int)w.y, false);              \
    f32x2 p3 = __builtin_amdgcn_cvt_pk_f32_fp8((int)w.y, true);               \
    acc0 += p0.x; acc1 += p0.y; acc2 += p1.x; acc3 += p1.y;                   \
    acc4 += p2.x; acc5 += p2.y; acc6 += p3.x; acc7 += p3.y;                   \
  }

// ushort col stream: 8 edges per 16B load
#define GATHER_F8(h8b)                                                        \
  int e = rowptr[v];                                                          \
  const int end = rowptr[v + 1];                                              \
  while (e < end && (e & 7)) { EDGE8(h8b, col[e]); ++e; }                     \
  for (; e + 8 <= end; e += 8) {                                              \
    short8v cw = *reinterpret_cast<const short8v*>(&col[e]);                  \
    EDGE8(h8b, (unsigned short)cw[0]); EDGE8(h8b, (unsigned short)cw[1]);     \
    EDGE8(h8b, (unsigned short)cw[2]); EDGE8(h8b, (unsigned short)cw[3]);     \
    EDGE8(h8b, (unsigned short)cw[4]); EDGE8(h8b, (unsigned short)cw[5]);     \
    EDGE8(h8b, (unsigned short)cw[6]); EDGE8(h8b, (unsigned short)cw[7]);     \
  }                                                                           \
  for (; e < end; ++e) { EDGE8(h8b, col[e]); }

// ---------------- agg1 (fp8 gather) + bias/relu + GEMM2 + fp8 h2' out ----------------
__global__ __launch_bounds__(256) void k_agg_gemm(
    const unsigned char* __restrict__ h8, const int* __restrict__ rowptr,
    const unsigned short* __restrict__ col, const float* __restrict__ dinv,
    const float* __restrict__ bias, const unsigned short* __restrict__ Wt2g,
    unsigned char* __restrict__ out8) {
  const int t = threadIdx.x, lane = t & 63, wv = t >> 6;
  const int g = lane >> 3, f0 = (lane & 7) * 8;
  const int vbase = blockIdx.x * 32;
  const int v = vbase + wv * 8 + g;
  const int lrow = wv * 8 + g;

  __shared__ unsigned short h1s[32][72];  // pad: 144B stride

  if (v < N_NODES) {
    const float sv = dinv[v];
    float acc0 = 0, acc1 = 0, acc2 = 0, acc3 = 0, acc4 = 0, acc5 = 0, acc6 = 0, acc7 = 0;
    EDGE8(h8, v)  // self-loop term
    GATHER_F8(h8)

    const float4 ba = *reinterpret_cast<const float4*>(&bias[f0]);
    const float4 bb = *reinterpret_cast<const float4*>(&bias[f0 + 4]);
    float v0 = fmaxf(fmaf(sv, acc0, ba.x), 0.0f);
    float v1 = fmaxf(fmaf(sv, acc1, ba.y), 0.0f);
    float v2 = fmaxf(fmaf(sv, acc2, ba.z), 0.0f);
    float v3 = fmaxf(fmaf(sv, acc3, ba.w), 0.0f);
    float v4 = fmaxf(fmaf(sv, acc4, bb.x), 0.0f);
    float v5 = fmaxf(fmaf(sv, acc5, bb.y), 0.0f);
    float v6 = fmaxf(fmaf(sv, acc6, bb.z), 0.0f);
    float v7 = fmaxf(fmaf(sv, acc7, bb.w), 0.0f);

    uint4 o;
    o.x = pack2(v0, v1); o.y = pack2(v2, v3);
    o.z = pack2(v4, v5); o.w = pack2(v6, v7);
    *reinterpret_cast<uint4*>(&h1s[lrow][f0]) = o;
  } else {
    uint4 z = {0, 0, 0, 0};
    *reinterpret_cast<uint4*>(&h1s[lrow][f0]) = z;
  }
  __syncthreads();

  // GEMM2: 32 nodes x 64 cols; wave wv owns cols [wv*16, wv*16+16); K=64.
  const int kh = (lane >> 4) * 8;
  f32x4 acc2r[2] = {};
#pragma unroll
  for (int rt = 0; rt < 2; ++rt) {
#pragma unroll
    for (int k0 = 0; k0 < 64; k0 += 32) {
      short8v a = *reinterpret_cast<const short8v*>(&h1s[rt * 16 + (lane & 15)][k0 + kh]);
      short8v b = *reinterpret_cast<const short8v*>(
          Wt2g + (size_t)(wv * 16 + (lane & 15)) * 64 + k0 + kh);
      acc2r[rt] = __builtin_amdgcn_mfma_f32_16x16x32_bf16(a, b, acc2r[rt], 0, 0, 0);
    }
  }
  // epilogue: h2'[r][c] = fp8( dinv[r] * acc )  (64B rows for agg2)
#pragma unroll
  for (int rt = 0; rt < 2; ++rt) {
#pragma unroll
    for (int j = 0; j < 4; ++j) {
      int vg = vbase + rt * 16 + (lane >> 4) * 4 + j;
      if (vg < N_NODES)
        out8[(size_t)vg * 64 + wv * 16 + (lane & 15)] = f2fp8(acc2r[rt][j] * dinv[vg]);
    }
  }
}

// ---------------- agg2 (fp8 gather) + classifier fused ----------------
__global__ __launch_bounds__(256) void k_agg_fin(
    const unsigned char* __restrict__ h8, const int* __restrict__ rowptr,
    const unsigned short* __restrict__ col, const float* __restrict__ dinv,
    const float* __restrict__ bias, const float* __restrict__ Wc,
    const float* __restrict__ bc, float* __restrict__ out) {
  const int t = threadIdx.x, lane = t & 63;
  const int g = lane >> 3, f0 = (lane & 7) * 8;
  const int v = blockIdx.x * 32 + (t >> 6) * 8 + g;
  if (v >= N_NODES) return;

  float acc0 = 0, acc1 = 0, acc2 = 0, acc3 = 0, acc4 = 0, acc5 = 0, acc6 = 0, acc7 = 0;
  EDGE8(h8, v)  // self-loop term
  GATHER_F8(h8)

  const float sv = dinv[v];
  const float4 ba = *reinterpret_cast<const float4*>(&bias[f0]);
  const float4 bb = *reinterpret_cast<const float4*>(&bias[f0 + 4]);
  const float4 wa = *reinterpret_cast<const float4*>(&Wc[f0]);
  const float4 wb = *reinterpret_cast<const float4*>(&Wc[f0 + 4]);
  float p = fmaxf(fmaf(sv, acc0, ba.x), 0.0f) * wa.x +
            fmaxf(fmaf(sv, acc1, ba.y), 0.0f) * wa.y +
            fmaxf(fmaf(sv, acc2, ba.z), 0.0f) * wa.z +
            fmaxf(fmaf(sv, acc3, ba.w), 0.0f) * wa.w +
            fmaxf(fmaf(sv, acc4, bb.x), 0.0f) * wb.x +
            fmaxf(fmaf(sv, acc5, bb.y), 0.0f) * wb.y +
            fmaxf(fmaf(sv, acc6, bb.z), 0.0f) * wb.z +
            fmaxf(fmaf(sv, acc7, bb.w), 0.0f) * wb.w;
  p += __shfl_xor(p, 1);
  p += __shfl_xor(p, 2);
  p += __shfl_xor(p, 4);
  if ((lane & 7) == 0) out[v] = 1.0f / (1.0f + expf(-(p + bc[0])));
}

extern "C" void kernel_launch(void* const* d_in, const int* in_sizes, int n_in,
                              void* d_out, int out_size, void* d_ws, size_t ws_size,
                              hipStream_t stream) {
  const float* x  = (const float*)d_in[0];
  const int*   ei = (const int*)d_in[1];
  const float* W1 = (const float*)d_in[2];
  const float* b1 = (const float*)d_in[3];
  const float* W2 = (const float*)d_in[4];
  const float* b2 = (const float*)d_in[5];
  const float* Wc = (const float*)d_in[6];
  const float* bc = (const float*)d_in[7];
  float* out = (float*)d_out;

  const int* src = ei;
  const int* dst = ei + N_EDGES;

  // workspace layout (u32 units)
  unsigned* w = (unsigned*)d_ws;
  int*   bcur   = (int*)(w + 0);                          // 256
  int*   rowptr = (int*)(w + 256);                        // 50432 (needs 50001)
  unsigned short* colidx = (unsigned short*)(w + 50688);  // 800000 ush = 400000 u32
  unsigned* ebuf = w + 450688;                            // 196*8192 = 1605632
  float* dinv   = (float*)(w + 2056320);                  // 50176
  unsigned short* Wt1g = (unsigned short*)(w + 2106496);  // 16384 ush
  unsigned short* Wt2g = (unsigned short*)(w + 2114688);  // 4096 ush
  unsigned short* A_bf = (unsigned short*)(w + 2116736);  // 3.2M ush (x@W1, unscaled)
  unsigned char*  A_f8 = (unsigned char*)(w + 3716736);   // 3.2M B (h1', fp8 scaled)
  unsigned char*  B_f8 = (unsigned char*)(w + 4516736);   // 3.2M B (h2', fp8 scaled)

  k_prep<<<3, 256, 0, stream>>>(bcur, W1, W2, Wt1g, Wt2g);
  // GEMM1 (unscaled) runs concurrently with dense-split in one dispatch
  k_g1split<<<NGB + NCH, 256, 0, stream>>>(x, Wt1g, A_bf, src, dst, bcur, ebuf);
  // CSR build (ushort col) + dinv + fp8 h1' emission
  k_bucket<<<NBKT, 256, 0, stream>>>(ebuf, bcur, rowptr, colidx, dinv, A_bf, A_f8);

  const int NAB = (N_NODES + 31) / 32;  // 1563
  k_agg_gemm<<<NAB, 256, 0, stream>>>(A_f8, rowptr, colidx, dinv, b1, Wt2g, B_f8);
  k_agg_fin<<<NAB, 256, 0, stream>>>(B_f8, rowptr, colidx, dinv, b2, Wc, bc, out);
}